// Round 5
// baseline (1068.684 us; speedup 1.0000x reference)
//
#include <hip/hip_runtime.h>

// ---------------------------------------------------------------------------
// TemporalAttnLayer: B=256, T=64, M=256, H=256
//
// Round-5: r4 structure (256 independent 1024-thr wgs, f16 dot2 GEMVs) plus:
//  - register-pinned weights: 8 uint4 of W_hh[j] + 2 uint4 of W_d slice per
//    thread (160 KB/CU) loaded once, reused all 64 steps
//  - LDS-pinned W_hh k8-slices 8..10 (48 KB), sharing space with the one-time
//    enc staging buffer
//  - y_til = sum_t beta_t * E_t  (E_t = sum_m w~_m enc[m][t], precomputed)
//    -> computed by the softmax wave, kills a barrier + full-wg reduction
//  - context: enc held in per-thread regs (16 f16), beta packed f16, 8 dot2
//  - 5 barriers/step (was 6)
// ---------------------------------------------------------------------------

#define Bx 256
#define Tx 64
#define Mx 256
#define Hx 256
#define NT 1024
#define ETS 66    // enc staging row stride in ushorts
#define XS 18     // swizzled chunk stride for x1/v_d

typedef unsigned int  uint;
typedef unsigned short ushort;
typedef _Float16 h2  __attribute__((ext_vector_type(2)));
typedef float    f2v __attribute__((ext_vector_type(2)));

__device__ __forceinline__ float4 ld4(const float* p) { return *(const float4*)p; }
__device__ __forceinline__ float h2f(ushort s) {
  union { ushort s; _Float16 h; } c; c.s = s; return (float)c.h;
}
__device__ __forceinline__ ushort f2h(float f) {
  union { _Float16 h; ushort s; } c; c.h = (_Float16)f; return c.s;
}
__device__ __forceinline__ uint pk2(float a, float b) {
  return (uint)f2h(a) | ((uint)f2h(b) << 16);
}
__device__ __forceinline__ float tanh_fast(float x) {
  float e2 = __expf(2.0f * x);
  return 1.0f - 2.0f / (e2 + 1.0f);
}
__device__ __forceinline__ float sigm(float x) {
  return 1.0f / (1.0f + __expf(-x));
}
__device__ __forceinline__ float wave_sum(float v) {
  #pragma unroll
  for (int o = 1; o < 64; o <<= 1) v += __shfl_xor(v, o, 64);
  return v;
}
__device__ __forceinline__ int xsw(int m) { return (m >> 4) * XS + (m & 15); }

#if defined(__has_builtin)
#if __has_builtin(__builtin_amdgcn_fdot2)
#define HAVE_FDOT2 1
#endif
#endif
__device__ __forceinline__ float dot2u(uint w, uint a, float acc) {
#ifdef HAVE_FDOT2
  h2 W = __builtin_bit_cast(h2, w);
  h2 A = __builtin_bit_cast(h2, a);
  return __builtin_amdgcn_fdot2(W, A, acc, false);
#else
  return acc + h2f((ushort)w) * h2f((ushort)a)
             + h2f((ushort)(w >> 16)) * h2f((ushort)(a >> 16));
#endif
}
__device__ __forceinline__ float dot8(uint4 w, uint4 a, float acc) {
  acc = dot2u(w.x, a.x, acc);
  acc = dot2u(w.y, a.y, acc);
  acc = dot2u(w.z, a.z, acc);
  acc = dot2u(w.w, a.w, acc);
  return acc;
}

// ---------------------------------------------------------------------------
// Pack kernel (unchanged from r4): fp32 -> f16 k8-major uint4; W_y transposed.
// ---------------------------------------------------------------------------
__global__ __launch_bounds__(256)
void pack_weights(const float* __restrict__ W_d,
                  const float* __restrict__ W_hh,
                  const float* __restrict__ U_d,
                  const float* __restrict__ W_y,
                  uint4* __restrict__ Whh8,
                  uint4* __restrict__ Wd8,
                  uint4* __restrict__ Ud8,
                  float* __restrict__ Wyt) {
  const int blk = blockIdx.x, tid = threadIdx.x;
  if (blk < 32) {
    const int k8 = blk;
    #pragma unroll
    for (int q = 0; q < 4; ++q) {
      const int j = tid + 256 * q;
      float4 a = ld4(W_hh + (size_t)j * 256 + 8 * k8);
      float4 b = ld4(W_hh + (size_t)j * 256 + 8 * k8 + 4);
      Whh8[k8 * 1024 + j] = uint4{pk2(a.x, a.y), pk2(a.z, a.w),
                                  pk2(b.x, b.y), pk2(b.z, b.w)};
    }
  } else if (blk < 96) {
    const int k8 = blk - 32;
    float4 a = ld4(W_d + (size_t)tid * 512 + 8 * k8);
    float4 b = ld4(W_d + (size_t)tid * 512 + 8 * k8 + 4);
    Wd8[k8 * 256 + tid] = uint4{pk2(a.x, a.y), pk2(a.z, a.w),
                                pk2(b.x, b.y), pk2(b.z, b.w)};
  } else if (blk < 128) {
    const int m8 = blk - 96;
    float4 a = ld4(U_d + (size_t)tid * 256 + 8 * m8);
    float4 b = ld4(U_d + (size_t)tid * 256 + 8 * m8 + 4);
    Ud8[m8 * 256 + tid] = uint4{pk2(a.x, a.y), pk2(a.z, a.w),
                                pk2(b.x, b.y), pk2(b.z, b.w)};
  } else {
    const int k0 = (blk - 128) * 4;
    float4 w = ld4(W_y + (size_t)tid * 512 + k0);
    Wyt[(k0 + 0) * 256 + tid] = w.x;
    Wyt[(k0 + 1) * 256 + tid] = w.y;
    Wyt[(k0 + 2) * 256 + tid] = w.z;
    Wyt[(k0 + 3) * 256 + tid] = w.w;
  }
}

// ---------------------------------------------------------------------------
// Main kernel
// ---------------------------------------------------------------------------
__global__ __launch_bounds__(NT, 4)
void fused(const float* __restrict__ enc,      // (T,B,M)
           const float* __restrict__ yv,       // (B,T,1)
           const float* __restrict__ b_Wd,     // (M)
           const float* __restrict__ v_d,      // (1,M)
           const float* __restrict__ w_tilda,  // (1,M+1)
           const float* __restrict__ b_wt,     // (1)
           const float* __restrict__ W_ih,     // (4H,1)
           const float* __restrict__ b_ih,     // (4H)
           const float* __restrict__ b_hh,     // (4H)
           const float* __restrict__ b_Wy,     // (H)
           const float* __restrict__ v_y,      // (1,H)
           const float* __restrict__ b_vy,     // (1)
           const uint4* __restrict__ Whh8,
           const uint4* __restrict__ Wd8,
           const uint4* __restrict__ Ud8,
           const float* __restrict__ Wyt,
           ushort* __restrict__ Y1,            // (B,T,M) f16 scratch
           float* __restrict__ out)            // (B,1)
{
  // 48 KB slab: stage 0 = enc staging ([m][ETS] f16); steady = Whh k8 8..10
  __shared__ __align__(16) uint4 slab[3 * 1024];
  __shared__ __align__(16) ushort dsp2_s[2 * Hx];   // [d|sp] f16-packed
  __shared__ float x1_s[16 * XS];
  __shared__ float vd_s[16 * XS];
  __shared__ float xpart_s[4 * 256];                // x1 partials; dcfin aliases
  __shared__ float gates_s[1024];                   // gates; epilogue partials
  __shared__ float c_s[256];
  __shared__ float l_s[Tx];
  __shared__ uint  beta2_s[Tx / 2];                 // beta packed f16 pairs
  __shared__ float e_s[Tx];                         // E_t
  __shared__ float red_s[4];
  __shared__ float ytil_s;

  float* dcfin_s = xpart_s;                         // [d|c] fp32, 2 KB alias

  const int b   = blockIdx.x;
  const int tid = threadIdx.x;     // 0..1023
  const int h   = tid & 255;
  const int p   = tid >> 8;        // 0..3
  const size_t BM = (size_t)Bx * Mx;
  ushort* encStage = (ushort*)slab;                 // stage-0 view

  // ---- stage 0a: enc[b] -> LDS staging, transposed f16 ----
  for (int i = tid; i < Tx * Mx; i += NT) {
    int t = i >> 8, m = i & 255;
    encStage[m * ETS + t] = f2h(enc[(size_t)t * BM + (size_t)b * Mx + m]);
  }
  if (tid < 256) vd_s[xsw(tid)] = v_d[tid];
  __syncthreads();  // S1: staging ready

  // ---- stage 0b: pull enc regs for context; E_t ----
  uint ereg[8];     // enc[m][16q .. 16q+16) as 8 f16-pairs, m=tid>>2, q=tid&3
  {
    const int m = tid >> 2, q = tid & 3;
    const ushort* er = encStage + m * ETS + q * 16;
    #pragma unroll
    for (int j = 0; j < 8; ++j) ereg[j] = *(const uint*)(er + 2 * j);
  }
  if (tid < Tx) {   // E_t = sum_m w~_m enc[m][t]
    float acc = 0.0f;
    for (int m = 0; m < Mx; ++m)
      acc += w_tilda[m] * h2f(encStage[m * ETS + tid]);
    e_s[tid] = acc;
  }
  __syncthreads();  // S2: staging consumers done

  // ---- stage 0c: weight pins (regs), LDS slab, state init ----
  uint4 wreg[8], xreg[2];
  #pragma unroll
  for (int i = 0; i < 8; ++i) wreg[i] = Whh8[i * 1024 + tid];        // k8 0..7
  #pragma unroll
  for (int i = 0; i < 2; ++i) xreg[i] = Wd8[(p * 16 + i) * 256 + h]; // k8 p16+i
  #pragma unroll
  for (int i = 0; i < 3; ++i)
    slab[i * 1024 + tid] = Whh8[(8 + i) * 1024 + tid];               // k8 8..10
  if (tid < 512) dsp2_s[tid] = 0;

  const float bj  = b_ih[tid] + b_hh[tid];
  float bWd_r = 0.f, wih0 = 0.f, wih1 = 0.f, wih2 = 0.f, wih3 = 0.f;
  if (tid < 256) {
    bWd_r = b_Wd[h];
    wih0 = W_ih[h]; wih1 = W_ih[h + 256]; wih2 = W_ih[h + 512]; wih3 = W_ih[h + 768];
  }
  const float wty = w_tilda[Mx];
  const float bwt = b_wt[0];

  // ---- stage 1: Y1[b] = enc[b] @ U_d^T (packed-fp32 FMA, f16 weights) ----
  {
    const int n = h;
    const float* eb = enc + (size_t)b * Mx;
    for (int tb = p * 16; tb < p * 16 + 16; tb += 8) {
      f2v acc2[8];
      #pragma unroll
      for (int j = 0; j < 8; ++j) acc2[j] = f2v{0.f, 0.f};
      #pragma unroll 2
      for (int m8 = 0; m8 < 32; ++m8) {
        uint4 u = Ud8[m8 * 256 + n];
        f2v w01 = f2v{h2f((ushort)u.x), h2f((ushort)(u.x >> 16))};
        f2v w23 = f2v{h2f((ushort)u.y), h2f((ushort)(u.y >> 16))};
        f2v w45 = f2v{h2f((ushort)u.z), h2f((ushort)(u.z >> 16))};
        f2v w67 = f2v{h2f((ushort)u.w), h2f((ushort)(u.w >> 16))};
        #pragma unroll
        for (int j = 0; j < 8; ++j) {
          const float* ep = eb + (size_t)(tb + j) * BM + 8 * m8;
          float4 ea = ld4(ep), eb4 = ld4(ep + 4);
          acc2[j] += f2v{ea.x, ea.y} * w01;
          acc2[j] += f2v{ea.z, ea.w} * w23;
          acc2[j] += f2v{eb4.x, eb4.y} * w45;
          acc2[j] += f2v{eb4.z, eb4.w} * w67;
        }
      }
      #pragma unroll
      for (int j = 0; j < 8; ++j)
        Y1[((size_t)b * Tx + tb + j) * Mx + n] = f2h(acc2[j].x + acc2[j].y);
    }
  }
  __syncthreads();  // S3: slab, state, Y1 ready

  float sp_reg = 0.0f;   // thread h's sp (tid < 256)

  for (int t = 0; t < Tx; ++t) {
    // ===== Phase A: gates (pinned regs + LDS slab + stream) + x1 partial ====
    {
      const uint4* dq = (const uint4*)dsp2_s;   // [d|sp]: d = dq[0..31]
      float g = bj;
      #pragma unroll
      for (int i = 0; i < 8; ++i)               // pinned regs, k8 0..7
        g = dot8(wreg[i], dq[i], g);
      #pragma unroll
      for (int i = 0; i < 3; ++i)               // LDS slab, k8 8..10
        g = dot8(slab[i * 1024 + tid], dq[8 + i], g);
      const uint4* wp = Whh8 + tid;
      #pragma unroll 7
      for (int k8 = 11; k8 < 32; ++k8)          // stream, k8 11..31
        g = dot8(wp[k8 * 1024], dq[k8], g);
      gates_s[tid] = g;
      // x1 partial over k8 in [16p, 16p+16)
      float xa = 0.0f;
      #pragma unroll
      for (int i = 0; i < 2; ++i)               // pinned
        xa = dot8(xreg[i], dq[p * 16 + i], xa);
      const uint4* xp = Wd8 + h;
      #pragma unroll 7
      for (int i = 2; i < 16; ++i)              // stream
        xa = dot8(xp[(p * 16 + i) * 256], dq[p * 16 + i], xa);
      xpart_s[p * 256 + h] = xa;
    }
    __syncthreads();  // B1: gates_s + xpart_s
    if (tid < 256) {
      x1_s[xsw(h)] = xpart_s[h] + xpart_s[256 + h] + xpart_s[512 + h]
                   + xpart_s[768 + h] + bWd_r;
    }
    __syncthreads();  // B2: x1_s

    // ===== Phase B: scores (16 lanes/query) =====
    {
      const int tq = tid >> 4, lq = tid & 15;
      const ushort* y1r = Y1 + ((size_t)b * Tx + tq) * Mx + lq * 16;
      const int base = lq * XS;
      uint4 q0 = *(const uint4*)(y1r);
      uint4 q1 = *(const uint4*)(y1r + 8);
      float ps = 0.0f;
      {
        uint qq[8] = {q0.x, q0.y, q0.z, q0.w, q1.x, q1.y, q1.z, q1.w};
        #pragma unroll
        for (int j = 0; j < 8; ++j) {
          float2 x2 = *(const float2*)&x1_s[base + 2 * j];
          float2 v2 = *(const float2*)&vd_s[base + 2 * j];
          ps += tanh_fast(x2.x + h2f((ushort)qq[j])) * v2.x
              + tanh_fast(x2.y + h2f((ushort)(qq[j] >> 16))) * v2.y;
        }
      }
      ps += __shfl_xor(ps, 1, 64);
      ps += __shfl_xor(ps, 2, 64);
      ps += __shfl_xor(ps, 4, 64);
      ps += __shfl_xor(ps, 8, 64);
      if (lq == 0) l_s[tq] = ps;
    }
    __syncthreads();  // B3: l_s
    if (tid < 64) {   // softmax + packed beta + ytil, all in wave 0
      float v = l_s[tid];
      float mx = v;
      #pragma unroll
      for (int o = 1; o < 64; o <<= 1) mx = fmaxf(mx, __shfl_xor(mx, o, 64));
      float e = __expf(v - mx);
      float sm = e;
      #pragma unroll
      for (int o = 1; o < 64; o <<= 1) sm += __shfl_xor(sm, o, 64);
      float beta = e / sm;
      float bpart = __shfl_xor(beta, 1, 64);
      if ((tid & 1) == 0) beta2_s[tid >> 1] = pk2(beta, bpart);
      float yt = wave_sum(beta * e_s[tid]);
      if (tid == 0) ytil_s = yt + wty * yv[b * Tx + t] + bwt;
    }
    __syncthreads();  // B4: beta2_s + ytil_s
    // context from enc regs: m = tid>>2, q = tid&3; 8 dot2
    {
      const int q = tid & 3;
      float acc = 0.0f;
      #pragma unroll
      for (int j = 0; j < 8; ++j)
        acc = dot2u(ereg[j], beta2_s[q * 8 + j], acc);
      acc += __shfl_xor(acc, 1, 64);
      acc += __shfl_xor(acc, 2, 64);
      if (q == 0) c_s[tid >> 2] = acc;
    }
    if (t == Tx - 1) __syncthreads();  // c_s complete before LSTM reads it
    // ===== Phase C: LSTM cell (tid < 256) =====
    if (tid < 256) {
      const float ytil = ytil_s;
      float fi = sigm(gates_s[h]       + ytil * wih0);
      float ff = sigm(gates_s[256 + h] + ytil * wih1);
      float fg = tanh_fast(gates_s[512 + h] + ytil * wih2);
      float fo = sigm(gates_s[768 + h] + ytil * wih3);
      float spn = ff * sp_reg + fi * fg;
      float dn  = fo * tanh_fast(spn);
      sp_reg = spn;
      dsp2_s[h]       = f2h(dn);
      dsp2_s[256 + h] = f2h(spn);
      if (t == Tx - 1) { dcfin_s[h] = dn; dcfin_s[256 + h] = c_s[h]; }
    }
    __syncthreads();  // B6: state ready for next step
  }

  // ===== Epilogue: out[b] = v_y . (W_y @ [d|c] + b_Wy) + b_vy =====
  {
    float a = 0.0f;
    const float* wy = Wyt + h;
    for (int k = 128 * p; k < 128 * p + 128; ++k)
      a += wy[(size_t)k * 256] * dcfin_s[k];
    gates_s[p * 256 + h] = a;     // gates_s reused as epilogue partials
  }
  __syncthreads();
  if (tid < 256) {
    float aa = gates_s[h] + gates_s[256 + h] + gates_s[512 + h] + gates_s[768 + h]
             + b_Wy[h];
    float po = aa * v_y[h];
    po = wave_sum(po);
    if ((tid & 63) == 0) red_s[tid >> 6] = po;
  }
  __syncthreads();
  if (tid == 0) out[b] = red_s[0] + red_s[1] + red_s[2] + red_s[3] + b_vy[0];
}

extern "C" void kernel_launch(void* const* d_in, const int* in_sizes, int n_in,
                              void* d_out, int out_size, void* d_ws, size_t ws_size,
                              hipStream_t stream) {
  const float* enc     = (const float*)d_in[0];
  const float* yv      = (const float*)d_in[1];
  const float* W_d     = (const float*)d_in[2];
  const float* b_Wd    = (const float*)d_in[3];
  const float* U_d     = (const float*)d_in[4];
  const float* v_d     = (const float*)d_in[5];
  const float* w_tilda = (const float*)d_in[6];
  const float* b_wt    = (const float*)d_in[7];
  const float* W_ih    = (const float*)d_in[8];
  const float* W_hh    = (const float*)d_in[9];
  const float* b_ih    = (const float*)d_in[10];
  const float* b_hh    = (const float*)d_in[11];
  const float* W_y     = (const float*)d_in[12];
  const float* b_Wy    = (const float*)d_in[13];
  const float* v_y     = (const float*)d_in[14];
  const float* b_vy    = (const float*)d_in[15];
  float* outp = (float*)d_out;

  char* ws = (char*)d_ws;
  uint4* Whh8 = (uint4*)ws;                                // 512 KB
  uint4* Wd8  = (uint4*)(ws + (512 << 10));                // 256 KB
  uint4* Ud8  = (uint4*)(ws + (768 << 10));                // 128 KB
  float* Wyt  = (float*)(ws + (896 << 10));                // 512 KB
  ushort* Y1  = (ushort*)(ws + (1408 << 10));              // 8 MB

  hipLaunchKernelGGL(pack_weights, dim3(256), dim3(256), 0, stream,
                     W_d, W_hh, U_d, W_y, Whh8, Wd8, Ud8, Wyt);
  hipLaunchKernelGGL(fused, dim3(Bx), dim3(NT), 0, stream,
                     enc, yv, b_Wd, v_d, w_tilda, b_wt, W_ih, b_ih, b_hh,
                     b_Wy, v_y, b_vy, Whh8, Wd8, Ud8, Wyt, Y1, outp);
}

// Round 6
// 1055.777 us; speedup vs baseline: 1.0122x; 1.0122x over previous
//
#include <hip/hip_runtime.h>

// ---------------------------------------------------------------------------
// TemporalAttnLayer: B=256, T=64, M=256, H=256
//
// Round-6 = Round-5 + the spill fix:
//   amdgpu_waves_per_eu(4,4) pins the compiler's occupancy assumption to
//   4 waves/EU (16 waves/CU = our actual 1 wg/CU), giving the allocator the
//   full 128-VGPR budget. r5's 40 VGPRs of pinned weights (8x uint4 W_hh row
//   chunk + 2x uint4 W_d chunk) then stay in registers instead of spilling
//   to scratch (r5: VGPR stuck at 64, FETCH 19->260 MB = scratch thrash).
// Structure otherwise r5: 256 independent 1024-thr wgs, f16 dot2 GEMVs,
// LDS-pinned W_hh k8 8..10, E_t-based ytil, 5 barriers/step.
// ---------------------------------------------------------------------------

#define Bx 256
#define Tx 64
#define Mx 256
#define Hx 256
#define NT 1024
#define ETS 66    // enc staging row stride in ushorts
#define XS 18     // swizzled chunk stride for x1/v_d

typedef unsigned int  uint;
typedef unsigned short ushort;
typedef _Float16 h2  __attribute__((ext_vector_type(2)));
typedef float    f2v __attribute__((ext_vector_type(2)));

__device__ __forceinline__ float4 ld4(const float* p) { return *(const float4*)p; }
__device__ __forceinline__ float h2f(ushort s) {
  union { ushort s; _Float16 h; } c; c.s = s; return (float)c.h;
}
__device__ __forceinline__ ushort f2h(float f) {
  union { _Float16 h; ushort s; } c; c.h = (_Float16)f; return c.s;
}
__device__ __forceinline__ uint pk2(float a, float b) {
  return (uint)f2h(a) | ((uint)f2h(b) << 16);
}
__device__ __forceinline__ float tanh_fast(float x) {
  float e2 = __expf(2.0f * x);
  return 1.0f - 2.0f / (e2 + 1.0f);
}
__device__ __forceinline__ float sigm(float x) {
  return 1.0f / (1.0f + __expf(-x));
}
__device__ __forceinline__ float wave_sum(float v) {
  #pragma unroll
  for (int o = 1; o < 64; o <<= 1) v += __shfl_xor(v, o, 64);
  return v;
}
__device__ __forceinline__ int xsw(int m) { return (m >> 4) * XS + (m & 15); }

#if defined(__has_builtin)
#if __has_builtin(__builtin_amdgcn_fdot2)
#define HAVE_FDOT2 1
#endif
#endif
__device__ __forceinline__ float dot2u(uint w, uint a, float acc) {
#ifdef HAVE_FDOT2
  h2 W = __builtin_bit_cast(h2, w);
  h2 A = __builtin_bit_cast(h2, a);
  return __builtin_amdgcn_fdot2(W, A, acc, false);
#else
  return acc + h2f((ushort)w) * h2f((ushort)a)
             + h2f((ushort)(w >> 16)) * h2f((ushort)(a >> 16));
#endif
}
__device__ __forceinline__ float dot8(uint4 w, uint4 a, float acc) {
  acc = dot2u(w.x, a.x, acc);
  acc = dot2u(w.y, a.y, acc);
  acc = dot2u(w.z, a.z, acc);
  acc = dot2u(w.w, a.w, acc);
  return acc;
}

// ---------------------------------------------------------------------------
// Pack kernel: fp32 -> f16 k8-major uint4; W_y transposed fp32.
// ---------------------------------------------------------------------------
__global__ __launch_bounds__(256)
void pack_weights(const float* __restrict__ W_d,
                  const float* __restrict__ W_hh,
                  const float* __restrict__ U_d,
                  const float* __restrict__ W_y,
                  uint4* __restrict__ Whh8,
                  uint4* __restrict__ Wd8,
                  uint4* __restrict__ Ud8,
                  float* __restrict__ Wyt) {
  const int blk = blockIdx.x, tid = threadIdx.x;
  if (blk < 32) {
    const int k8 = blk;
    #pragma unroll
    for (int q = 0; q < 4; ++q) {
      const int j = tid + 256 * q;
      float4 a = ld4(W_hh + (size_t)j * 256 + 8 * k8);
      float4 b = ld4(W_hh + (size_t)j * 256 + 8 * k8 + 4);
      Whh8[k8 * 1024 + j] = uint4{pk2(a.x, a.y), pk2(a.z, a.w),
                                  pk2(b.x, b.y), pk2(b.z, b.w)};
    }
  } else if (blk < 96) {
    const int k8 = blk - 32;
    float4 a = ld4(W_d + (size_t)tid * 512 + 8 * k8);
    float4 b = ld4(W_d + (size_t)tid * 512 + 8 * k8 + 4);
    Wd8[k8 * 256 + tid] = uint4{pk2(a.x, a.y), pk2(a.z, a.w),
                                pk2(b.x, b.y), pk2(b.z, b.w)};
  } else if (blk < 128) {
    const int m8 = blk - 96;
    float4 a = ld4(U_d + (size_t)tid * 256 + 8 * m8);
    float4 b = ld4(U_d + (size_t)tid * 256 + 8 * m8 + 4);
    Ud8[m8 * 256 + tid] = uint4{pk2(a.x, a.y), pk2(a.z, a.w),
                                pk2(b.x, b.y), pk2(b.z, b.w)};
  } else {
    const int k0 = (blk - 128) * 4;
    float4 w = ld4(W_y + (size_t)tid * 512 + k0);
    Wyt[(k0 + 0) * 256 + tid] = w.x;
    Wyt[(k0 + 1) * 256 + tid] = w.y;
    Wyt[(k0 + 2) * 256 + tid] = w.z;
    Wyt[(k0 + 3) * 256 + tid] = w.w;
  }
}

// ---------------------------------------------------------------------------
// Main kernel: one 1024-thread wg per batch element, fully independent.
// amdgpu_waves_per_eu(4,4): exactly 4 waves/SIMD -> 128-VGPR budget, no spill.
// ---------------------------------------------------------------------------
__global__ __launch_bounds__(NT) __attribute__((amdgpu_waves_per_eu(4, 4)))
void fused(const float* __restrict__ enc,      // (T,B,M)
           const float* __restrict__ yv,       // (B,T,1)
           const float* __restrict__ b_Wd,     // (M)
           const float* __restrict__ v_d,      // (1,M)
           const float* __restrict__ w_tilda,  // (1,M+1)
           const float* __restrict__ b_wt,     // (1)
           const float* __restrict__ W_ih,     // (4H,1)
           const float* __restrict__ b_ih,     // (4H)
           const float* __restrict__ b_hh,     // (4H)
           const float* __restrict__ b_Wy,     // (H)
           const float* __restrict__ v_y,      // (1,H)
           const float* __restrict__ b_vy,     // (1)
           const uint4* __restrict__ Whh8,
           const uint4* __restrict__ Wd8,
           const uint4* __restrict__ Ud8,
           const float* __restrict__ Wyt,
           ushort* __restrict__ Y1,            // (B,T,M) f16 scratch
           float* __restrict__ out)            // (B,1)
{
  // 48 KB slab: stage 0 = enc staging ([m][ETS] f16); steady = Whh k8 8..10
  __shared__ __align__(16) uint4 slab[3 * 1024];
  __shared__ __align__(16) ushort dsp2_s[2 * Hx];   // [d|sp] f16-packed
  __shared__ float x1_s[16 * XS];
  __shared__ float vd_s[16 * XS];
  __shared__ float xpart_s[4 * 256];                // x1 partials; dcfin aliases
  __shared__ float gates_s[1024];                   // gates; epilogue partials
  __shared__ float c_s[256];
  __shared__ float l_s[Tx];
  __shared__ uint  beta2_s[Tx / 2];                 // beta packed f16 pairs
  __shared__ float e_s[Tx];                         // E_t
  __shared__ float red_s[4];
  __shared__ float ytil_s;

  float* dcfin_s = xpart_s;                         // [d|c] fp32 alias

  const int b   = blockIdx.x;
  const int tid = threadIdx.x;     // 0..1023
  const int h   = tid & 255;
  const int p   = tid >> 8;        // 0..3
  const size_t BM = (size_t)Bx * Mx;
  ushort* encStage = (ushort*)slab;                 // stage-0 view

  // ---- stage 0a: enc[b] -> LDS staging, transposed f16 ----
  for (int i = tid; i < Tx * Mx; i += NT) {
    int t = i >> 8, m = i & 255;
    encStage[m * ETS + t] = f2h(enc[(size_t)t * BM + (size_t)b * Mx + m]);
  }
  if (tid < 256) vd_s[xsw(tid)] = v_d[tid];
  __syncthreads();  // S1: staging ready

  // ---- stage 0b: pull enc regs for context; E_t ----
  uint ereg[8];     // enc[m][16q..16q+16) as 8 f16-pairs, m=tid>>2, q=tid&3
  {
    const int m = tid >> 2, q = tid & 3;
    const ushort* er = encStage + m * ETS + q * 16;
    #pragma unroll
    for (int j = 0; j < 8; ++j) ereg[j] = *(const uint*)(er + 2 * j);
  }
  if (tid < Tx) {   // E_t = sum_m w~_m enc[m][t]
    float acc = 0.0f;
    for (int m = 0; m < Mx; ++m)
      acc += w_tilda[m] * h2f(encStage[m * ETS + tid]);
    e_s[tid] = acc;
  }
  __syncthreads();  // S2: staging consumers done

  // ---- stage 0c: weight pins (regs), LDS slab, state init ----
  uint4 wreg[8], xreg[2];
  #pragma unroll
  for (int i = 0; i < 8; ++i) wreg[i] = Whh8[i * 1024 + tid];        // k8 0..7
  #pragma unroll
  for (int i = 0; i < 2; ++i) xreg[i] = Wd8[(p * 16 + i) * 256 + h]; // k8 p16+i
  #pragma unroll
  for (int i = 0; i < 3; ++i)
    slab[i * 1024 + tid] = Whh8[(8 + i) * 1024 + tid];               // k8 8..10
  if (tid < 512) dsp2_s[tid] = 0;

  const float bj  = b_ih[tid] + b_hh[tid];
  float bWd_r = 0.f, wih0 = 0.f, wih1 = 0.f, wih2 = 0.f, wih3 = 0.f;
  if (tid < 256) {
    bWd_r = b_Wd[h];
    wih0 = W_ih[h]; wih1 = W_ih[h + 256]; wih2 = W_ih[h + 512]; wih3 = W_ih[h + 768];
  }
  const float wty = w_tilda[Mx];
  const float bwt = b_wt[0];

  // ---- stage 1: Y1[b] = enc[b] @ U_d^T (packed-fp32 FMA, f16 weights) ----
  {
    const int n = h;
    const float* eb = enc + (size_t)b * Mx;
    for (int tb = p * 16; tb < p * 16 + 16; tb += 8) {
      f2v acc2[8];
      #pragma unroll
      for (int j = 0; j < 8; ++j) acc2[j] = f2v{0.f, 0.f};
      #pragma unroll 2
      for (int m8 = 0; m8 < 32; ++m8) {
        uint4 u = Ud8[m8 * 256 + n];
        f2v w01 = f2v{h2f((ushort)u.x), h2f((ushort)(u.x >> 16))};
        f2v w23 = f2v{h2f((ushort)u.y), h2f((ushort)(u.y >> 16))};
        f2v w45 = f2v{h2f((ushort)u.z), h2f((ushort)(u.z >> 16))};
        f2v w67 = f2v{h2f((ushort)u.w), h2f((ushort)(u.w >> 16))};
        #pragma unroll
        for (int j = 0; j < 8; ++j) {
          const float* ep = eb + (size_t)(tb + j) * BM + 8 * m8;
          float4 ea = ld4(ep), eb4 = ld4(ep + 4);
          acc2[j] += f2v{ea.x, ea.y} * w01;
          acc2[j] += f2v{ea.z, ea.w} * w23;
          acc2[j] += f2v{eb4.x, eb4.y} * w45;
          acc2[j] += f2v{eb4.z, eb4.w} * w67;
        }
      }
      #pragma unroll
      for (int j = 0; j < 8; ++j)
        Y1[((size_t)b * Tx + tb + j) * Mx + n] = f2h(acc2[j].x + acc2[j].y);
    }
  }
  __syncthreads();  // S3: slab, state, Y1 ready

  float sp_reg = 0.0f;   // thread h's sp (tid < 256)

  for (int t = 0; t < Tx; ++t) {
    // ===== Phase A: gates (pinned regs + LDS slab + stream) + x1 partial ====
    {
      const uint4* dq = (const uint4*)dsp2_s;   // [d|sp]: d = dq[0..31]
      float g = bj;
      #pragma unroll
      for (int i = 0; i < 8; ++i)               // pinned regs, k8 0..7
        g = dot8(wreg[i], dq[i], g);
      #pragma unroll
      for (int i = 0; i < 3; ++i)               // LDS slab, k8 8..10
        g = dot8(slab[i * 1024 + tid], dq[8 + i], g);
      const uint4* wp = Whh8 + tid;
      #pragma unroll 7
      for (int k8 = 11; k8 < 32; ++k8)          // stream, k8 11..31
        g = dot8(wp[k8 * 1024], dq[k8], g);
      gates_s[tid] = g;
      // x1 partial over k8 in [16p, 16p+16)
      float xa = 0.0f;
      #pragma unroll
      for (int i = 0; i < 2; ++i)               // pinned
        xa = dot8(xreg[i], dq[p * 16 + i], xa);
      const uint4* xp = Wd8 + h;
      #pragma unroll 7
      for (int i = 2; i < 16; ++i)              // stream
        xa = dot8(xp[(p * 16 + i) * 256], dq[p * 16 + i], xa);
      xpart_s[p * 256 + h] = xa;
    }
    __syncthreads();  // B1: gates_s + xpart_s
    if (tid < 256) {
      x1_s[xsw(h)] = xpart_s[h] + xpart_s[256 + h] + xpart_s[512 + h]
                   + xpart_s[768 + h] + bWd_r;
    }
    __syncthreads();  // B2: x1_s

    // ===== Phase B: scores (16 lanes/query) =====
    {
      const int tq = tid >> 4, lq = tid & 15;
      const ushort* y1r = Y1 + ((size_t)b * Tx + tq) * Mx + lq * 16;
      const int base = lq * XS;
      uint4 q0 = *(const uint4*)(y1r);
      uint4 q1 = *(const uint4*)(y1r + 8);
      float ps = 0.0f;
      {
        uint qq[8] = {q0.x, q0.y, q0.z, q0.w, q1.x, q1.y, q1.z, q1.w};
        #pragma unroll
        for (int j = 0; j < 8; ++j) {
          float2 x2 = *(const float2*)&x1_s[base + 2 * j];
          float2 v2 = *(const float2*)&vd_s[base + 2 * j];
          ps += tanh_fast(x2.x + h2f((ushort)qq[j])) * v2.x
              + tanh_fast(x2.y + h2f((ushort)(qq[j] >> 16))) * v2.y;
        }
      }
      ps += __shfl_xor(ps, 1, 64);
      ps += __shfl_xor(ps, 2, 64);
      ps += __shfl_xor(ps, 4, 64);
      ps += __shfl_xor(ps, 8, 64);
      if (lq == 0) l_s[tq] = ps;
    }
    __syncthreads();  // B3: l_s
    if (tid < 64) {   // softmax + packed beta + ytil, all in wave 0
      float v = l_s[tid];
      float mx = v;
      #pragma unroll
      for (int o = 1; o < 64; o <<= 1) mx = fmaxf(mx, __shfl_xor(mx, o, 64));
      float e = __expf(v - mx);
      float sm = e;
      #pragma unroll
      for (int o = 1; o < 64; o <<= 1) sm += __shfl_xor(sm, o, 64);
      float beta = e / sm;
      float bpart = __shfl_xor(beta, 1, 64);
      if ((tid & 1) == 0) beta2_s[tid >> 1] = pk2(beta, bpart);
      float yt = wave_sum(beta * e_s[tid]);
      if (tid == 0) ytil_s = yt + wty * yv[b * Tx + t] + bwt;
    }
    __syncthreads();  // B4: beta2_s + ytil_s
    // context from enc regs: m = tid>>2, q = tid&3; 8 dot2
    {
      const int q = tid & 3;
      float acc = 0.0f;
      #pragma unroll
      for (int j = 0; j < 8; ++j)
        acc = dot2u(ereg[j], beta2_s[q * 8 + j], acc);
      acc += __shfl_xor(acc, 1, 64);
      acc += __shfl_xor(acc, 2, 64);
      if (q == 0) c_s[tid >> 2] = acc;
    }
    if (t == Tx - 1) __syncthreads();  // c_s complete before LSTM reads it
    // ===== Phase C: LSTM cell (tid < 256) =====
    if (tid < 256) {
      const float ytil = ytil_s;
      float fi = sigm(gates_s[h]       + ytil * wih0);
      float ff = sigm(gates_s[256 + h] + ytil * wih1);
      float fg = tanh_fast(gates_s[512 + h] + ytil * wih2);
      float fo = sigm(gates_s[768 + h] + ytil * wih3);
      float spn = ff * sp_reg + fi * fg;
      float dn  = fo * tanh_fast(spn);
      sp_reg = spn;
      dsp2_s[h]       = f2h(dn);
      dsp2_s[256 + h] = f2h(spn);
      if (t == Tx - 1) { dcfin_s[h] = dn; dcfin_s[256 + h] = c_s[h]; }
    }
    __syncthreads();  // B5: state ready for next step
  }

  // ===== Epilogue: out[b] = v_y . (W_y @ [d|c] + b_Wy) + b_vy =====
  {
    float a = 0.0f;
    const float* wy = Wyt + h;
    for (int k = 128 * p; k < 128 * p + 128; ++k)
      a += wy[(size_t)k * 256] * dcfin_s[k];
    gates_s[p * 256 + h] = a;     // gates_s reused as epilogue partials
  }
  __syncthreads();
  if (tid < 256) {
    float aa = gates_s[h] + gates_s[256 + h] + gates_s[512 + h] + gates_s[768 + h]
             + b_Wy[h];
    float po = aa * v_y[h];
    po = wave_sum(po);
    if ((tid & 63) == 0) red_s[tid >> 6] = po;
  }
  __syncthreads();
  if (tid == 0) out[b] = red_s[0] + red_s[1] + red_s[2] + red_s[3] + b_vy[0];
}

extern "C" void kernel_launch(void* const* d_in, const int* in_sizes, int n_in,
                              void* d_out, int out_size, void* d_ws, size_t ws_size,
                              hipStream_t stream) {
  const float* enc     = (const float*)d_in[0];
  const float* yv      = (const float*)d_in[1];
  const float* W_d     = (const float*)d_in[2];
  const float* b_Wd    = (const float*)d_in[3];
  const float* U_d     = (const float*)d_in[4];
  const float* v_d     = (const float*)d_in[5];
  const float* w_tilda = (const float*)d_in[6];
  const float* b_wt    = (const float*)d_in[7];
  const float* W_ih    = (const float*)d_in[8];
  const float* W_hh    = (const float*)d_in[9];
  const float* b_ih    = (const float*)d_in[10];
  const float* b_hh    = (const float*)d_in[11];
  const float* W_y     = (const float*)d_in[12];
  const float* b_Wy    = (const float*)d_in[13];
  const float* v_y     = (const float*)d_in[14];
  const float* b_vy    = (const float*)d_in[15];
  float* outp = (float*)d_out;

  char* ws = (char*)d_ws;
  uint4* Whh8 = (uint4*)ws;                                // 512 KB
  uint4* Wd8  = (uint4*)(ws + (512 << 10));                // 256 KB
  uint4* Ud8  = (uint4*)(ws + (768 << 10));                // 128 KB
  float* Wyt  = (float*)(ws + (896 << 10));                // 512 KB
  ushort* Y1  = (ushort*)(ws + (1408 << 10));              // 8 MB

  hipLaunchKernelGGL(pack_weights, dim3(256), dim3(256), 0, stream,
                     W_d, W_hh, U_d, W_y, Whh8, Wd8, Ud8, Wyt);
  hipLaunchKernelGGL(fused, dim3(Bx), dim3(NT), 0, stream,
                     enc, yv, b_Wd, v_d, w_tilda, b_wt, W_ih, b_ih, b_hh,
                     b_Wy, v_y, b_vy, Whh8, Wd8, Ud8, Wyt, Y1, outp);
}

// Round 7
// 1052.445 us; speedup vs baseline: 1.0154x; 1.0032x over previous
//
#include <hip/hip_runtime.h>

// ---------------------------------------------------------------------------
// TemporalAttnLayer: B=256, T=64, M=256, H=256
//
// Round-7: r4 structure (256 independent 1024-thr wgs, f16 dot2 GEMVs,
// weights streamed from L2, NO register pinning) with overhead reduction:
//  - 4 barriers/step (was 6): scores consume x1 partials directly; ytil via
//    precomputed E_t inside the softmax wave
//  - per-thread order [x1part] B1 [gates][scores] B3 [softmax] B4 [LSTM] B5:
//    gates' weight stream overlaps scores' tanh work across waves
//  - yv in softmax-wave registers; context via dot2 on packed beta
// r5/r6 lesson: pinned-weight VGPR tiles spill (VGPR stuck at 64, FETCH
// 19->266 MB scratch thrash) -- reverted for good.
// ---------------------------------------------------------------------------

#define Bx 256
#define Tx 64
#define Mx 256
#define Hx 256
#define NT 1024
#define ETS 66    // encT_s row stride in ushorts

typedef unsigned int  uint;
typedef unsigned short ushort;
typedef _Float16 h2  __attribute__((ext_vector_type(2)));
typedef float    f2v __attribute__((ext_vector_type(2)));

__device__ __forceinline__ float4 ld4(const float* p) { return *(const float4*)p; }
__device__ __forceinline__ float h2f(ushort s) {
  union { ushort s; _Float16 h; } c; c.s = s; return (float)c.h;
}
__device__ __forceinline__ ushort f2h(float f) {
  union { _Float16 h; ushort s; } c; c.h = (_Float16)f; return c.s;
}
__device__ __forceinline__ uint pk2(float a, float b) {
  return (uint)f2h(a) | ((uint)f2h(b) << 16);
}
__device__ __forceinline__ float tanh_fast(float x) {
  float e2 = __expf(2.0f * x);
  return 1.0f - 2.0f / (e2 + 1.0f);
}
__device__ __forceinline__ float sigm(float x) {
  return 1.0f / (1.0f + __expf(-x));
}
__device__ __forceinline__ float wave_sum(float v) {
  #pragma unroll
  for (int o = 1; o < 64; o <<= 1) v += __shfl_xor(v, o, 64);
  return v;
}

#if defined(__has_builtin)
#if __has_builtin(__builtin_amdgcn_fdot2)
#define HAVE_FDOT2 1
#endif
#endif
__device__ __forceinline__ float dot2u(uint w, uint a, float acc) {
#ifdef HAVE_FDOT2
  h2 W = __builtin_bit_cast(h2, w);
  h2 A = __builtin_bit_cast(h2, a);
  return __builtin_amdgcn_fdot2(W, A, acc, false);
#else
  return acc + h2f((ushort)w) * h2f((ushort)a)
             + h2f((ushort)(w >> 16)) * h2f((ushort)(a >> 16));
#endif
}
__device__ __forceinline__ float dot8(uint4 w, uint4 a, float acc) {
  acc = dot2u(w.x, a.x, acc);
  acc = dot2u(w.y, a.y, acc);
  acc = dot2u(w.z, a.z, acc);
  acc = dot2u(w.w, a.w, acc);
  return acc;
}

// ---------------------------------------------------------------------------
// Pack kernel: fp32 -> f16 k8-major uint4; W_y transposed fp32.
//   Whh8[k8][j]  k8<32, j<1024 : uint4 = f16(W_hh[j][8k8..+7])   (512 KB)
//   Wd8 [k8][n]  k8<64, n<256  : uint4 = f16(W_d[n][8k8..+7])    (256 KB)
//   Ud8 [m8][n]  m8<32, n<256  : uint4 = f16(U_d[n][8m8..+7])    (128 KB)
//   Wyt [k][h]   k<512         : float = W_y[h][k]               (512 KB)
// ---------------------------------------------------------------------------
__global__ __launch_bounds__(256)
void pack_weights(const float* __restrict__ W_d,
                  const float* __restrict__ W_hh,
                  const float* __restrict__ U_d,
                  const float* __restrict__ W_y,
                  uint4* __restrict__ Whh8,
                  uint4* __restrict__ Wd8,
                  uint4* __restrict__ Ud8,
                  float* __restrict__ Wyt) {
  const int blk = blockIdx.x, tid = threadIdx.x;
  if (blk < 32) {
    const int k8 = blk;
    #pragma unroll
    for (int q = 0; q < 4; ++q) {
      const int j = tid + 256 * q;
      float4 a = ld4(W_hh + (size_t)j * 256 + 8 * k8);
      float4 b = ld4(W_hh + (size_t)j * 256 + 8 * k8 + 4);
      Whh8[k8 * 1024 + j] = uint4{pk2(a.x, a.y), pk2(a.z, a.w),
                                  pk2(b.x, b.y), pk2(b.z, b.w)};
    }
  } else if (blk < 96) {
    const int k8 = blk - 32;
    float4 a = ld4(W_d + (size_t)tid * 512 + 8 * k8);
    float4 b = ld4(W_d + (size_t)tid * 512 + 8 * k8 + 4);
    Wd8[k8 * 256 + tid] = uint4{pk2(a.x, a.y), pk2(a.z, a.w),
                                pk2(b.x, b.y), pk2(b.z, b.w)};
  } else if (blk < 128) {
    const int m8 = blk - 96;
    float4 a = ld4(U_d + (size_t)tid * 256 + 8 * m8);
    float4 b = ld4(U_d + (size_t)tid * 256 + 8 * m8 + 4);
    Ud8[m8 * 256 + tid] = uint4{pk2(a.x, a.y), pk2(a.z, a.w),
                                pk2(b.x, b.y), pk2(b.z, b.w)};
  } else {
    const int k0 = (blk - 128) * 4;
    float4 w = ld4(W_y + (size_t)tid * 512 + k0);
    Wyt[(k0 + 0) * 256 + tid] = w.x;
    Wyt[(k0 + 1) * 256 + tid] = w.y;
    Wyt[(k0 + 2) * 256 + tid] = w.z;
    Wyt[(k0 + 3) * 256 + tid] = w.w;
  }
}

// ---------------------------------------------------------------------------
// Main kernel: one 1024-thread wg per batch element, fully independent.
// ---------------------------------------------------------------------------
__global__ __launch_bounds__(NT, 4)
void fused(const float* __restrict__ enc,      // (T,B,M)
           const float* __restrict__ yv,       // (B,T,1)
           const float* __restrict__ b_Wd,     // (M)
           const float* __restrict__ v_d,      // (1,M)
           const float* __restrict__ w_tilda,  // (1,M+1)
           const float* __restrict__ b_wt,     // (1)
           const float* __restrict__ W_ih,     // (4H,1)
           const float* __restrict__ b_ih,     // (4H)
           const float* __restrict__ b_hh,     // (4H)
           const float* __restrict__ b_Wy,     // (H)
           const float* __restrict__ v_y,      // (1,H)
           const float* __restrict__ b_vy,     // (1)
           const uint4* __restrict__ Whh8,
           const uint4* __restrict__ Wd8,
           const uint4* __restrict__ Ud8,
           const float* __restrict__ Wyt,
           ushort* __restrict__ Y1,            // (B,T,M) f16 scratch
           float* __restrict__ out)            // (B,1)
{
  __shared__ ushort encT_s[Mx * ETS];               // 33.8 KB [m][t] f16
  __shared__ __align__(16) ushort dsp2_s[2 * Hx];   // [d|sp] f16-packed
  __shared__ float vd_s[Mx];                        // v_d, plain layout
  __shared__ float xpart_s[4 * 256];                // x1 partials (+bias on p0)
  __shared__ float gates_s[1024];                   // gates; epilogue partials
  __shared__ float c_s[256];
  __shared__ float l_s[Tx];
  __shared__ uint  beta2_s[Tx / 2];                 // beta packed f16 pairs
  __shared__ float e_s[Tx];                         // E_t
  __shared__ float red_s[4];
  __shared__ float ytil_s;

  float* dcfin_s = xpart_s;                         // [d|c] fp32 alias (512)

  const int b   = blockIdx.x;
  const int tid = threadIdx.x;     // 0..1023
  const int h   = tid & 255;
  const int p   = tid >> 8;        // 0..3
  const size_t BM = (size_t)Bx * Mx;

  // ---- stage 0: enc[b] -> LDS transposed f16; params; state ----
  for (int i = tid; i < Tx * Mx; i += NT) {
    int t = i >> 8, m = i & 255;
    encT_s[m * ETS + t] = f2h(enc[(size_t)t * BM + (size_t)b * Mx + m]);
  }
  if (tid < 256) vd_s[tid] = v_d[tid];
  if (tid < 512) dsp2_s[tid] = 0;

  const float bj  = b_ih[tid] + b_hh[tid];     // bias of gate j = tid
  float bWd_r = 0.f, wih0 = 0.f, wih1 = 0.f, wih2 = 0.f, wih3 = 0.f;
  if (tid < 256) {
    bWd_r = b_Wd[h];                            // p==0 threads carry the bias
    wih0 = W_ih[h]; wih1 = W_ih[h + 256]; wih2 = W_ih[h + 512]; wih3 = W_ih[h + 768];
  }
  const float wty = w_tilda[Mx];
  const float bwt = b_wt[0];
  float yv_r = 0.f;
  if (tid < Tx) yv_r = yv[b * Tx + tid];        // softmax wave: yv[b][t] regs

  // ---- stage 1: Y1[b] = enc[b] @ U_d^T (packed-fp32 FMA, f16 weights) ----
  {
    const int n = h;
    const float* eb = enc + (size_t)b * Mx;
    for (int tb = p * 16; tb < p * 16 + 16; tb += 8) {
      f2v acc2[8];
      #pragma unroll
      for (int j = 0; j < 8; ++j) acc2[j] = f2v{0.f, 0.f};
      #pragma unroll 2
      for (int m8 = 0; m8 < 32; ++m8) {
        uint4 u = Ud8[m8 * 256 + n];
        f2v w01 = f2v{h2f((ushort)u.x), h2f((ushort)(u.x >> 16))};
        f2v w23 = f2v{h2f((ushort)u.y), h2f((ushort)(u.y >> 16))};
        f2v w45 = f2v{h2f((ushort)u.z), h2f((ushort)(u.z >> 16))};
        f2v w67 = f2v{h2f((ushort)u.w), h2f((ushort)(u.w >> 16))};
        #pragma unroll
        for (int j = 0; j < 8; ++j) {
          const float* ep = eb + (size_t)(tb + j) * BM + 8 * m8;
          float4 ea = ld4(ep), eb4 = ld4(ep + 4);
          acc2[j] += f2v{ea.x, ea.y} * w01;
          acc2[j] += f2v{ea.z, ea.w} * w23;
          acc2[j] += f2v{eb4.x, eb4.y} * w45;
          acc2[j] += f2v{eb4.z, eb4.w} * w67;
        }
      }
      #pragma unroll
      for (int j = 0; j < 8; ++j)
        Y1[((size_t)b * Tx + tb + j) * Mx + n] = f2h(acc2[j].x + acc2[j].y);
    }
  }
  __syncthreads();  // S1: encT_s, dsp2_s, vd_s, Y1 ready

  // ---- stage 0b: E_t = sum_m w~_m enc[m][t] (one-time, softmax wave) ----
  if (tid < Tx) {
    float acc = 0.0f;
    for (int m = 0; m < Mx; ++m)
      acc += w_tilda[m] * h2f(encT_s[m * ETS + tid]);
    e_s[tid] = acc;
  }
  __syncthreads();  // S2: e_s ready

  float sp_reg = 0.0f;   // thread h's sp (tid < 256)

  for (int t = 0; t < Tx; ++t) {
    const uint4* dq = (const uint4*)dsp2_s;   // 64 x uint4 = [d|sp] f16

    // ===== A1: x1 partials, K-split by p (16 dot8) =====
    {
      float xa = bWd_r;                        // 0 for p>0
      const uint4* xp = Wd8 + h + (p * 16) * 256;
      #pragma unroll
      for (int i = 0; i < 16; ++i)
        xa = dot8(xp[i * 256], dq[p * 16 + i], xa);
      xpart_s[p * 256 + h] = xa;
    }
    __syncthreads();  // B1: xpart_s ready

    // ===== A2: gates (stream-heavy, overlaps scores of other waves) =====
    {
      float g = bj;
      const uint4* wp = Whh8 + tid;
      #pragma unroll 8
      for (int k8 = 0; k8 < 32; ++k8)
        g = dot8(wp[k8 * 1024], dq[k8], g);
      gates_s[tid] = g;
    }
    // ===== B: scores from partials (16 lanes/query) =====
    {
      const int tq = tid >> 4, lq = tid & 15;
      const ushort* y1r = Y1 + ((size_t)b * Tx + tq) * Mx + lq * 16;
      uint4 q0 = *(const uint4*)(y1r);
      uint4 q1 = *(const uint4*)(y1r + 8);
      const float* xp = xpart_s + lq * 16;
      const float* vp = vd_s + lq * 16;
      float ps = 0.0f;
      uint qq[8] = {q0.x, q0.y, q0.z, q0.w, q1.x, q1.y, q1.z, q1.w};
      #pragma unroll
      for (int j4 = 0; j4 < 4; ++j4) {          // 4 m's per iter
        float4 a0 = *(const float4*)(xp + 4 * j4);
        float4 a1 = *(const float4*)(xp + 256 + 4 * j4);
        float4 a2 = *(const float4*)(xp + 512 + 4 * j4);
        float4 a3 = *(const float4*)(xp + 768 + 4 * j4);
        float4 vv = *(const float4*)(vp + 4 * j4);
        float x0 = a0.x + a1.x + a2.x + a3.x;
        float x1 = a0.y + a1.y + a2.y + a3.y;
        float x2 = a0.z + a1.z + a2.z + a3.z;
        float x3 = a0.w + a1.w + a2.w + a3.w;
        uint qa = qq[2 * j4], qb = qq[2 * j4 + 1];
        ps += tanh_fast(x0 + h2f((ushort)qa)) * vv.x
            + tanh_fast(x1 + h2f((ushort)(qa >> 16))) * vv.y
            + tanh_fast(x2 + h2f((ushort)qb)) * vv.z
            + tanh_fast(x3 + h2f((ushort)(qb >> 16))) * vv.w;
      }
      ps += __shfl_xor(ps, 1, 64);
      ps += __shfl_xor(ps, 2, 64);
      ps += __shfl_xor(ps, 4, 64);
      ps += __shfl_xor(ps, 8, 64);
      if (lq == 0) l_s[tq] = ps;
    }
    __syncthreads();  // B3: l_s + gates_s ready

    // ===== softmax + beta pack + ytil, all inside wave 0 =====
    if (tid < 64) {
      float v = l_s[tid];
      float mx = v;
      #pragma unroll
      for (int o = 1; o < 64; o <<= 1) mx = fmaxf(mx, __shfl_xor(mx, o, 64));
      float e = __expf(v - mx);
      float sm = e;
      #pragma unroll
      for (int o = 1; o < 64; o <<= 1) sm += __shfl_xor(sm, o, 64);
      float beta = e / sm;
      float bnext = __shfl_xor(beta, 1, 64);
      if ((tid & 1) == 0) beta2_s[tid >> 1] = pk2(beta, bnext);
      float term = beta * e_s[tid] + ((tid == t) ? (wty * yv_r + bwt) : 0.0f);
      float yt = wave_sum(term);
      if (tid == 0) ytil_s = yt;
    }
    __syncthreads();  // B4: beta2_s + ytil_s ready

    // ===== context (in-wave) =====
    {
      const int m = tid >> 2, q = tid & 3;
      const ushort* er = encT_s + m * ETS + q * 16;
      float acc = 0.0f;
      #pragma unroll
      for (int j = 0; j < 8; ++j)
        acc = dot2u(*(const uint*)(er + 2 * j), beta2_s[q * 8 + j], acc);
      acc += __shfl_xor(acc, 1, 64);
      acc += __shfl_xor(acc, 2, 64);
      if (q == 0 && t == Tx - 1) c_s[m] = acc;
    }
    if (t == Tx - 1) __syncthreads();  // c_s visible to LSTM threads

    // ===== LSTM cell (tid < 256) =====
    if (tid < 256) {
      const float ytil = ytil_s;
      float fi = sigm(gates_s[h]       + ytil * wih0);
      float ff = sigm(gates_s[256 + h] + ytil * wih1);
      float fg = tanh_fast(gates_s[512 + h] + ytil * wih2);
      float fo = sigm(gates_s[768 + h] + ytil * wih3);
      float spn = ff * sp_reg + fi * fg;
      float dn  = fo * tanh_fast(spn);
      sp_reg = spn;
      dsp2_s[h]       = f2h(dn);
      dsp2_s[256 + h] = f2h(spn);
      if (t == Tx - 1) { dcfin_s[h] = dn; dcfin_s[256 + h] = c_s[h]; }
    }
    __syncthreads();  // B5: state ready for next step
  }

  // ===== Epilogue: out[b] = v_y . (W_y @ [d|c] + b_Wy) + b_vy =====
  {
    float a = 0.0f;
    const float* wy = Wyt + h;
    for (int k = 128 * p; k < 128 * p + 128; ++k)
      a += wy[(size_t)k * 256] * dcfin_s[k];
    gates_s[p * 256 + h] = a;     // gates_s reused as epilogue partials
  }
  __syncthreads();
  if (tid < 256) {
    float aa = gates_s[h] + gates_s[256 + h] + gates_s[512 + h] + gates_s[768 + h]
             + b_Wy[h];
    float po = aa * v_y[h];
    po = wave_sum(po);
    if ((tid & 63) == 0) red_s[tid >> 6] = po;
  }
  __syncthreads();
  if (tid == 0) out[b] = red_s[0] + red_s[1] + red_s[2] + red_s[3] + b_vy[0];
}

extern "C" void kernel_launch(void* const* d_in, const int* in_sizes, int n_in,
                              void* d_out, int out_size, void* d_ws, size_t ws_size,
                              hipStream_t stream) {
  const float* enc     = (const float*)d_in[0];
  const float* yv      = (const float*)d_in[1];
  const float* W_d     = (const float*)d_in[2];
  const float* b_Wd    = (const float*)d_in[3];
  const float* U_d     = (const float*)d_in[4];
  const float* v_d     = (const float*)d_in[5];
  const float* w_tilda = (const float*)d_in[6];
  const float* b_wt    = (const float*)d_in[7];
  const float* W_ih    = (const float*)d_in[8];
  const float* W_hh    = (const float*)d_in[9];
  const float* b_ih    = (const float*)d_in[10];
  const float* b_hh    = (const float*)d_in[11];
  const float* W_y     = (const float*)d_in[12];
  const float* b_Wy    = (const float*)d_in[13];
  const float* v_y     = (const float*)d_in[14];
  const float* b_vy    = (const float*)d_in[15];
  float* outp = (float*)d_out;

  char* ws = (char*)d_ws;
  uint4* Whh8 = (uint4*)ws;                                // 512 KB
  uint4* Wd8  = (uint4*)(ws + (512 << 10));                // 256 KB
  uint4* Ud8  = (uint4*)(ws + (768 << 10));                // 128 KB
  float* Wyt  = (float*)(ws + (896 << 10));                // 512 KB
  ushort* Y1  = (ushort*)(ws + (1408 << 10));              // 8 MB

  hipLaunchKernelGGL(pack_weights, dim3(256), dim3(256), 0, stream,
                     W_d, W_hh, U_d, W_y, Whh8, Wd8, Ud8, Wyt);
  hipLaunchKernelGGL(fused, dim3(Bx), dim3(NT), 0, stream,
                     enc, yv, b_Wd, v_d, w_tilda, b_wt, W_ih, b_ih, b_hh,
                     b_Wy, v_y, b_vy, Whh8, Wd8, Ud8, Wyt, Y1, outp);
}

// Round 8
// 867.294 us; speedup vs baseline: 1.2322x; 1.2135x over previous
//
#include <hip/hip_runtime.h>

// ---------------------------------------------------------------------------
// TemporalAttnLayer: B=256, T=64, M=256, H=256
//
// Round-8: WAVE SPECIALIZATION on the r4 base (256 independent 1024-thr wgs).
//  - waves 0-7  (tid<512): gates GEMV only (j=tid, tid+512), streams Whh8
//  - waves 8-15 (tid>=512): x1 K-halves -> LDS-flag sync (subset only; gate
//    waves stream through it) -> scores (XS=20 swizzle, conflict-free) ->
//    flag -> wave 8 softmax + ytil (E_t trick); waves 8-11 run the LSTM
//  - 2 wg-wide barriers/step (was 6); subset syncs = monotone LDS counters
//  - context computed ONCE (t=63 after the loop); per-step c is unused since
//    ytil = sum_t beta_t E_t
//  - 64-VGPR discipline: gates unroll 4, no per-thread arrays, no pinning
//    (r5/r6/r7: allocator caps this kernel at 64 VGPRs; exceeding = scratch)
// ---------------------------------------------------------------------------

#define Bx 256
#define Tx 64
#define Mx 256
#define Hx 256
#define NT 1024
#define ETS 66    // encT_s row stride in ushorts
#define XS 20     // swizzle chunk stride (floats): 80B -> 16B-aligned, 2-way max

typedef unsigned int  uint;
typedef unsigned short ushort;
typedef _Float16 h2  __attribute__((ext_vector_type(2)));
typedef float    f2v __attribute__((ext_vector_type(2)));

__device__ __forceinline__ float4 ld4(const float* p) { return *(const float4*)p; }
__device__ __forceinline__ float h2f(ushort s) {
  union { ushort s; _Float16 h; } c; c.s = s; return (float)c.h;
}
__device__ __forceinline__ ushort f2h(float f) {
  union { _Float16 h; ushort s; } c; c.h = (_Float16)f; return c.s;
}
__device__ __forceinline__ uint pk2(float a, float b) {
  return (uint)f2h(a) | ((uint)f2h(b) << 16);
}
__device__ __forceinline__ float tanh_fast(float x) {
  float e2 = __expf(2.0f * x);
  return 1.0f - 2.0f / (e2 + 1.0f);
}
__device__ __forceinline__ float sigm(float x) {
  return 1.0f / (1.0f + __expf(-x));
}
__device__ __forceinline__ float wave_sum(float v) {
  #pragma unroll
  for (int o = 1; o < 64; o <<= 1) v += __shfl_xor(v, o, 64);
  return v;
}
__device__ __forceinline__ int xsw(int m) { return (m >> 4) * XS + (m & 15); }

#if defined(__has_builtin)
#if __has_builtin(__builtin_amdgcn_fdot2)
#define HAVE_FDOT2 1
#endif
#endif
__device__ __forceinline__ float dot2u(uint w, uint a, float acc) {
#ifdef HAVE_FDOT2
  h2 W = __builtin_bit_cast(h2, w);
  h2 A = __builtin_bit_cast(h2, a);
  return __builtin_amdgcn_fdot2(W, A, acc, false);
#else
  return acc + h2f((ushort)w) * h2f((ushort)a)
             + h2f((ushort)(w >> 16)) * h2f((ushort)(a >> 16));
#endif
}
__device__ __forceinline__ float dot8(uint4 w, uint4 a, float acc) {
  acc = dot2u(w.x, a.x, acc);
  acc = dot2u(w.y, a.y, acc);
  acc = dot2u(w.z, a.z, acc);
  acc = dot2u(w.w, a.w, acc);
  return acc;
}

// ---------------------------------------------------------------------------
// Pack kernel: fp32 -> f16 k8-major uint4; W_y transposed fp32.
// ---------------------------------------------------------------------------
__global__ __launch_bounds__(256)
void pack_weights(const float* __restrict__ W_d,
                  const float* __restrict__ W_hh,
                  const float* __restrict__ U_d,
                  const float* __restrict__ W_y,
                  uint4* __restrict__ Whh8,
                  uint4* __restrict__ Wd8,
                  uint4* __restrict__ Ud8,
                  float* __restrict__ Wyt) {
  const int blk = blockIdx.x, tid = threadIdx.x;
  if (blk < 32) {
    const int k8 = blk;
    #pragma unroll
    for (int q = 0; q < 4; ++q) {
      const int j = tid + 256 * q;
      float4 a = ld4(W_hh + (size_t)j * 256 + 8 * k8);
      float4 b = ld4(W_hh + (size_t)j * 256 + 8 * k8 + 4);
      Whh8[k8 * 1024 + j] = uint4{pk2(a.x, a.y), pk2(a.z, a.w),
                                  pk2(b.x, b.y), pk2(b.z, b.w)};
    }
  } else if (blk < 96) {
    const int k8 = blk - 32;
    float4 a = ld4(W_d + (size_t)tid * 512 + 8 * k8);
    float4 b = ld4(W_d + (size_t)tid * 512 + 8 * k8 + 4);
    Wd8[k8 * 256 + tid] = uint4{pk2(a.x, a.y), pk2(a.z, a.w),
                                pk2(b.x, b.y), pk2(b.z, b.w)};
  } else if (blk < 128) {
    const int m8 = blk - 96;
    float4 a = ld4(U_d + (size_t)tid * 256 + 8 * m8);
    float4 b = ld4(U_d + (size_t)tid * 256 + 8 * m8 + 4);
    Ud8[m8 * 256 + tid] = uint4{pk2(a.x, a.y), pk2(a.z, a.w),
                                pk2(b.x, b.y), pk2(b.z, b.w)};
  } else {
    const int k0 = (blk - 128) * 4;
    float4 w = ld4(W_y + (size_t)tid * 512 + k0);
    Wyt[(k0 + 0) * 256 + tid] = w.x;
    Wyt[(k0 + 1) * 256 + tid] = w.y;
    Wyt[(k0 + 2) * 256 + tid] = w.z;
    Wyt[(k0 + 3) * 256 + tid] = w.w;
  }
}

// ---------------------------------------------------------------------------
// Main kernel: one 1024-thread wg per batch element, fully independent.
// ---------------------------------------------------------------------------
__global__ __launch_bounds__(NT, 4)
void fused(const float* __restrict__ enc,      // (T,B,M)
           const float* __restrict__ yv,       // (B,T,1)
           const float* __restrict__ b_Wd,     // (M)
           const float* __restrict__ v_d,      // (1,M)
           const float* __restrict__ w_tilda,  // (1,M+1)
           const float* __restrict__ b_wt,     // (1)
           const float* __restrict__ W_ih,     // (4H,1)
           const float* __restrict__ b_ih,     // (4H)
           const float* __restrict__ b_hh,     // (4H)
           const float* __restrict__ b_Wy,     // (H)
           const float* __restrict__ v_y,      // (1,H)
           const float* __restrict__ b_vy,     // (1)
           const uint4* __restrict__ Whh8,
           const uint4* __restrict__ Wd8,
           const uint4* __restrict__ Ud8,
           const float* __restrict__ Wyt,
           ushort* __restrict__ Y1,            // (B,T,M) f16 scratch
           float* __restrict__ out)            // (B,1)
{
  __shared__ ushort encT_s[Mx * ETS];               // 33.8 KB [m][t] f16
  __shared__ __align__(16) ushort dsp2_s[2 * Hx];   // [d|sp] f16-packed
  __shared__ __align__(16) float xq_s[2 * 16 * XS]; // x1 K-half partials, swz
  __shared__ __align__(16) float vd_s[16 * XS];     // v_d swizzled
  __shared__ float gates_s[1024];                   // gates; epilogue partials
  __shared__ float dcfin_s[2 * Hx];                 // [d|c] fp32 (epilogue)
  __shared__ float l_s[Tx];
  __shared__ uint  beta2_s[Tx / 2];                 // beta packed f16 pairs
  __shared__ float e_s[Tx];                         // E_t
  __shared__ float red_s[4];
  __shared__ float ytil_s;
  __shared__ unsigned flagX, flagL;

  const int b   = blockIdx.x;
  const int tid = threadIdx.x;     // 0..1023
  const int h   = tid & 255;
  const int p   = tid >> 8;        // 0..3
  const size_t BM = (size_t)Bx * Mx;

  // ---- stage 0: enc[b] -> LDS transposed f16; params; state; flags ----
  for (int i = tid; i < Tx * Mx; i += NT) {
    int t = i >> 8, m = i & 255;
    encT_s[m * ETS + t] = f2h(enc[(size_t)t * BM + (size_t)b * Mx + m]);
  }
  if (tid < 256) vd_s[xsw(tid)] = v_d[tid];
  if (tid < 512) dsp2_s[tid] = 0;
  if (tid == 0) { flagX = 0u; flagL = 0u; }

  // role-specific parameter registers
  float bj0 = 0.f, bj1 = 0.f;                  // gate waves
  if (tid < 512) { bj0 = b_ih[tid] + b_hh[tid]; bj1 = b_ih[tid + 512] + b_hh[tid + 512]; }
  float bWd_r = 0.f;                           // x1 half-0 threads (idx<256)
  if (tid >= 512 && tid < 768) bWd_r = b_Wd[tid - 512];
  float wih0 = 0.f, wih1 = 0.f, wih2 = 0.f, wih3 = 0.f;  // LSTM threads
  if (tid >= 512 && tid < 768) {
    const int hh = tid - 512;
    wih0 = W_ih[hh]; wih1 = W_ih[hh + 256]; wih2 = W_ih[hh + 512]; wih3 = W_ih[hh + 768];
  }
  float yv_r = 0.f;                            // softmax wave (tid 512..575)
  if (tid >= 512 && tid < 576) yv_r = yv[b * Tx + (tid - 512)];
  const float wty = w_tilda[Mx];
  const float bwt = b_wt[0];

  // ---- stage 1: Y1[b] = enc[b] @ U_d^T (packed-fp32 FMA, f16 weights) ----
  {
    const int n = h;
    const float* eb = enc + (size_t)b * Mx;
    for (int tb = p * 16; tb < p * 16 + 16; tb += 8) {
      f2v acc2[8];
      #pragma unroll
      for (int j = 0; j < 8; ++j) acc2[j] = f2v{0.f, 0.f};
      #pragma unroll 2
      for (int m8 = 0; m8 < 32; ++m8) {
        uint4 u = Ud8[m8 * 256 + n];
        f2v w01 = f2v{h2f((ushort)u.x), h2f((ushort)(u.x >> 16))};
        f2v w23 = f2v{h2f((ushort)u.y), h2f((ushort)(u.y >> 16))};
        f2v w45 = f2v{h2f((ushort)u.z), h2f((ushort)(u.z >> 16))};
        f2v w67 = f2v{h2f((ushort)u.w), h2f((ushort)(u.w >> 16))};
        #pragma unroll
        for (int j = 0; j < 8; ++j) {
          const float* ep = eb + (size_t)(tb + j) * BM + 8 * m8;
          float4 ea = ld4(ep), eb4 = ld4(ep + 4);
          acc2[j] += f2v{ea.x, ea.y} * w01;
          acc2[j] += f2v{ea.z, ea.w} * w23;
          acc2[j] += f2v{eb4.x, eb4.y} * w45;
          acc2[j] += f2v{eb4.z, eb4.w} * w67;
        }
      }
      #pragma unroll
      for (int j = 0; j < 8; ++j)
        Y1[((size_t)b * Tx + tb + j) * Mx + n] = f2h(acc2[j].x + acc2[j].y);
    }
  }
  __syncthreads();  // S1: encT_s, dsp2_s, vd_s, flags, Y1 ready

  // ---- stage 0b: E_t = sum_m w~_m enc[m][t] (one-time) ----
  if (tid < Tx) {
    float acc = 0.0f;
    for (int m = 0; m < Mx; ++m)
      acc += w_tilda[m] * h2f(encT_s[m * ETS + tid]);
    e_s[tid] = acc;
  }
  __syncthreads();  // S2: e_s ready

  float sp_reg = 0.0f;   // LSTM threads (tid 512..767)

  for (int t = 0; t < Tx; ++t) {
    const uint4* dq = (const uint4*)dsp2_s;   // 64 x uint4 = [d|sp] f16

    if (tid < 512) {
      // ===== GATE WAVES: 2 outputs j=tid, tid+512; streams 512 KB =====
      float g0 = bj0, g1 = bj1;
      const uint4* wp = Whh8 + tid;
      #pragma unroll 4
      for (int k8 = 0; k8 < 32; ++k8) {
        uint4 a = dq[k8];                      // LDS broadcast
        g0 = dot8(wp[k8 * 1024], a, g0);
        g1 = dot8(wp[k8 * 1024 + 512], a, g1);
      }
      gates_s[tid] = g0;
      gates_s[tid + 512] = g1;
    } else {
      // ===== SCORE WAVES =====
      const int idx = tid - 512;               // 0..511
      const int m = idx & 255, q = idx >> 8;   // x1: output m, K-half q
      {
        float xa = (q == 0) ? bWd_r : 0.0f;
        const uint4* xp = Wd8 + m + (q * 32) * 256;
        #pragma unroll 8
        for (int i = 0; i < 32; ++i)
          xa = dot8(xp[i * 256], dq[q * 32 + i], xa);
        xq_s[q * (16 * XS) + xsw(m)] = xa;
      }
      __threadfence_block();
      if ((threadIdx.x & 63) == 0)
        __hip_atomic_fetch_add(&flagX, 1u, __ATOMIC_RELEASE, __HIP_MEMORY_SCOPE_WORKGROUP);
      const unsigned tgtX = 8u * (unsigned)(t + 1);
      while (__hip_atomic_load(&flagX, __ATOMIC_ACQUIRE, __HIP_MEMORY_SCOPE_WORKGROUP) < tgtX) {}

      // scores: 8 lanes/query, lane covers 32 m's
      {
        const int tq = idx >> 3, lq = idx & 7;
        const ushort* y1r = Y1 + ((size_t)b * Tx + tq) * Mx + lq * 32;
        float ps = 0.0f;
        #pragma unroll
        for (int g = 0; g < 8; ++g) {
          const int c   = 2 * lq + (g >> 2);
          const int off = c * XS + 4 * (g & 3);
          float4 xa0 = *(const float4*)(xq_s + off);
          float4 xa1 = *(const float4*)(xq_s + 16 * XS + off);
          float4 vv  = *(const float4*)(vd_s + off);
          uint2 yy = *(const uint2*)(y1r + 4 * g);
          ps += tanh_fast(xa0.x + xa1.x + h2f((ushort)yy.x)) * vv.x
              + tanh_fast(xa0.y + xa1.y + h2f((ushort)(yy.x >> 16))) * vv.y
              + tanh_fast(xa0.z + xa1.z + h2f((ushort)yy.y)) * vv.z
              + tanh_fast(xa0.w + xa1.w + h2f((ushort)(yy.y >> 16))) * vv.w;
        }
        ps += __shfl_xor(ps, 1, 64);
        ps += __shfl_xor(ps, 2, 64);
        ps += __shfl_xor(ps, 4, 64);
        if (lq == 0) l_s[tq] = ps;
      }
      __threadfence_block();
      if ((threadIdx.x & 63) == 0)
        __hip_atomic_fetch_add(&flagL, 1u, __ATOMIC_RELEASE, __HIP_MEMORY_SCOPE_WORKGROUP);

      if (idx < 64) {
        // softmax + beta pack + ytil (wave 8 only)
        const unsigned tgtL = 8u * (unsigned)(t + 1);
        while (__hip_atomic_load(&flagL, __ATOMIC_ACQUIRE, __HIP_MEMORY_SCOPE_WORKGROUP) < tgtL) {}
        float v = l_s[idx];
        float mx = v;
        #pragma unroll
        for (int o = 1; o < 64; o <<= 1) mx = fmaxf(mx, __shfl_xor(mx, o, 64));
        float e = __expf(v - mx);
        float sm = e;
        #pragma unroll
        for (int o = 1; o < 64; o <<= 1) sm += __shfl_xor(sm, o, 64);
        float beta = e / sm;
        float bnext = __shfl_xor(beta, 1, 64);
        if ((idx & 1) == 0) beta2_s[idx >> 1] = pk2(beta, bnext);
        float term = beta * e_s[idx] + ((idx == t) ? (wty * yv_r + bwt) : 0.0f);
        float yt = wave_sum(term);
        if (idx == 0) ytil_s = yt;
      }
    }
    __syncthreads();  // B_end: gates_s + ytil_s (+beta2_s) ready

    // ===== LSTM cell: threads 512..767 =====
    if (tid >= 512 && tid < 768) {
      const int hh = tid - 512;
      const float ytil = ytil_s;
      float fi = sigm(gates_s[hh]       + ytil * wih0);
      float ff = sigm(gates_s[256 + hh] + ytil * wih1);
      float fg = tanh_fast(gates_s[512 + hh] + ytil * wih2);
      float fo = sigm(gates_s[768 + hh] + ytil * wih3);
      float spn = ff * sp_reg + fi * fg;
      float dn  = fo * tanh_fast(spn);
      sp_reg = spn;
      dsp2_s[hh]       = f2h(dn);
      dsp2_s[256 + hh] = f2h(spn);
      if (t == Tx - 1) dcfin_s[hh] = dn;
    }
    __syncthreads();  // B_state: d/sp(t) ready
  }

  // ===== one-time context c (t=63): threads 512..1023, 2 lanes per m =====
  if (tid >= 512) {
    const int idx = tid - 512;
    const int m = idx >> 1, q = idx & 1;
    const ushort* er = encT_s + m * ETS + q * 32;
    float acc = 0.0f;
    #pragma unroll
    for (int j = 0; j < 16; ++j)
      acc = dot2u(*(const uint*)(er + 2 * j), beta2_s[q * 16 + j], acc);
    acc += __shfl_xor(acc, 1, 64);
    if (q == 0) dcfin_s[256 + m] = acc;
  }
  __syncthreads();

  // ===== Epilogue: out[b] = v_y . (W_y @ [d|c] + b_Wy) + b_vy =====
  {
    float a = 0.0f;
    const float* wy = Wyt + h;
    for (int k = 128 * p; k < 128 * p + 128; ++k)
      a += wy[(size_t)k * 256] * dcfin_s[k];
    gates_s[p * 256 + h] = a;     // gates_s reused as epilogue partials
  }
  __syncthreads();
  if (tid < 256) {
    float aa = gates_s[h] + gates_s[256 + h] + gates_s[512 + h] + gates_s[768 + h]
             + b_Wy[h];
    float po = aa * v_y[h];
    po = wave_sum(po);
    if ((tid & 63) == 0) red_s[tid >> 6] = po;
  }
  __syncthreads();
  if (tid == 0) out[b] = red_s[0] + red_s[1] + red_s[2] + red_s[3] + b_vy[0];
}

extern "C" void kernel_launch(void* const* d_in, const int* in_sizes, int n_in,
                              void* d_out, int out_size, void* d_ws, size_t ws_size,
                              hipStream_t stream) {
  const float* enc     = (const float*)d_in[0];
  const float* yv      = (const float*)d_in[1];
  const float* W_d     = (const float*)d_in[2];
  const float* b_Wd    = (const float*)d_in[3];
  const float* U_d     = (const float*)d_in[4];
  const float* v_d     = (const float*)d_in[5];
  const float* w_tilda = (const float*)d_in[6];
  const float* b_wt    = (const float*)d_in[7];
  const float* W_ih    = (const float*)d_in[8];
  const float* W_hh    = (const float*)d_in[9];
  const float* b_ih    = (const float*)d_in[10];
  const float* b_hh    = (const float*)d_in[11];
  const float* W_y     = (const float*)d_in[12];
  const float* b_Wy    = (const float*)d_in[13];
  const float* v_y     = (const float*)d_in[14];
  const float* b_vy    = (const float*)d_in[15];
  float* outp = (float*)d_out;

  char* ws = (char*)d_ws;
  uint4* Whh8 = (uint4*)ws;                                // 512 KB
  uint4* Wd8  = (uint4*)(ws + (512 << 10));                // 256 KB
  uint4* Ud8  = (uint4*)(ws + (768 << 10));                // 128 KB
  float* Wyt  = (float*)(ws + (896 << 10));                // 512 KB
  ushort* Y1  = (ushort*)(ws + (1408 << 10));              // 8 MB

  hipLaunchKernelGGL(pack_weights, dim3(256), dim3(256), 0, stream,
                     W_d, W_hh, U_d, W_y, Whh8, Wd8, Ud8, Wyt);
  hipLaunchKernelGGL(fused, dim3(Bx), dim3(NT), 0, stream,
                     enc, yv, b_Wd, v_d, w_tilda, b_wt, W_ih, b_ih, b_hh,
                     b_Wy, v_y, b_vy, Whh8, Wd8, Ud8, Wyt, Y1, outp);
}

// Round 10
// 722.635 us; speedup vs baseline: 1.4789x; 1.2002x over previous
//
#include <hip/hip_runtime.h>

// ---------------------------------------------------------------------------
// TemporalAttnLayer: B=256, T=64, M=256, H=256
//
// Round-10 = Round-9 (fp8 weight stream on the r8 wave-specialized base)
// with the compile fix: __builtin_amdgcn_cvt_pk_f32_fp8's word-select must be
// an immediate -> dec2 is now template<bool HI>.
//  - W_hh, W_d packed to fp8 e4m3 (x16 scale; /16 after the dot)
//  - decode: cvt_pk_f32_fp8 (2 w/op) + packed-f32 FMA; d/sp state f32 in LDS
//  - stream 768 -> 384 KB/step/CU (L2-BW bound halved); LDS ~12.5 KB
//  - waves 0-7 gates; waves 8-15 x1 -> flag -> scores -> flag -> softmax;
//    2 wg barriers/step; context once at t=63; 64-VGPR discipline
// ---------------------------------------------------------------------------

#define Bx 256
#define Tx 64
#define Mx 256
#define Hx 256
#define NT 1024
#define XS 20     // swizzle chunk stride (floats) for xq/vd

typedef unsigned int  uint;
typedef unsigned short ushort;
typedef _Float16 h2  __attribute__((ext_vector_type(2)));
typedef float    f2v __attribute__((ext_vector_type(2)));

__device__ __forceinline__ float4 ld4(const float* p) { return *(const float4*)p; }
__device__ __forceinline__ float h2f(ushort s) {
  union { ushort s; _Float16 h; } c; c.s = s; return (float)c.h;
}
__device__ __forceinline__ ushort f2h(float f) {
  union { _Float16 h; ushort s; } c; c.h = (_Float16)f; return c.s;
}
__device__ __forceinline__ uint pk2(float a, float b) {
  return (uint)f2h(a) | ((uint)f2h(b) << 16);
}
__device__ __forceinline__ float tanh_fast(float x) {
  float e2 = __expf(2.0f * x);
  return 1.0f - 2.0f / (e2 + 1.0f);
}
__device__ __forceinline__ float sigm(float x) {
  return 1.0f / (1.0f + __expf(-x));
}
__device__ __forceinline__ float wave_sum(float v) {
  #pragma unroll
  for (int o = 1; o < 64; o <<= 1) v += __shfl_xor(v, o, 64);
  return v;
}
__device__ __forceinline__ int xsw(int m) { return (m >> 4) * XS + (m & 15); }

#if defined(__has_builtin)
#if __has_builtin(__builtin_amdgcn_fdot2)
#define HAVE_FDOT2 1
#endif
#if __has_builtin(__builtin_amdgcn_cvt_pk_f32_fp8) && __has_builtin(__builtin_amdgcn_cvt_pk_fp8_f32)
#define HAVE_FP8 1
#endif
#endif

__device__ __forceinline__ float dot2u(uint w, uint a, float acc) {
#ifdef HAVE_FDOT2
  h2 W = __builtin_bit_cast(h2, w);
  h2 A = __builtin_bit_cast(h2, a);
  return __builtin_amdgcn_fdot2(W, A, acc, false);
#else
  return acc + h2f((ushort)w) * h2f((ushort)a)
             + h2f((ushort)(w >> 16)) * h2f((ushort)(a >> 16));
#endif
}

// ---- fp8 e4m3fn encode/decode (HW path + software fallback) ----
__device__ __forceinline__ uint sw8(float f) {          // float -> e4m3fn byte
  union { float f; uint u; } c; c.f = f;
  uint s = (c.u >> 31) << 7;
  float a = fabsf(f);
  if (!(a >= 0.0009765625f)) return s;
  if (a >= 448.f) return s | 0x7e;
  int e = (int)((c.u >> 23) & 0xff) - 127;
  if (e < -6) { int q = (int)(a * 512.f + 0.5f); return s | (uint)q; }
  uint m = ((c.u & 0x7fffff) + 0x80000) >> 20;
  if (m == 8) { m = 0; ++e; }
  if (e > 8) return s | 0x7e;
  return s | ((uint)(e + 7) << 3) | m;
}
__device__ __forceinline__ float sw8d(uint b) {         // e4m3fn byte -> float
  uint s = b >> 7, e = (b >> 3) & 0xf, m = b & 7;
  float v;
  if (e) { union { uint u; float f; } c; c.u = ((e + 120u) << 23) | (m << 20); v = c.f; }
  else v = (float)m * 0.001953125f;
  return s ? -v : v;
}
__device__ __forceinline__ uint pk_fp8x4(float w0, float w1, float w2, float w3) {
#ifdef HAVE_FP8
  int u = 0;
  u = __builtin_amdgcn_cvt_pk_fp8_f32(w0, w1, u, false);   // literal selectors
  u = __builtin_amdgcn_cvt_pk_fp8_f32(w2, w3, u, true);
  return (uint)u;
#else
  return sw8(w0) | (sw8(w1) << 8) | (sw8(w2) << 16) | (sw8(w3) << 24);
#endif
}
template <bool HI>
__device__ __forceinline__ f2v dec2(uint w) {           // 2 fp8 -> 2 f32
#ifdef HAVE_FP8
  return __builtin_amdgcn_cvt_pk_f32_fp8((int)w, HI);   // HI is constexpr
#else
  uint b0 = HI ? ((w >> 16) & 0xffu) : (w & 0xffu);
  uint b1 = HI ? (w >> 24) : ((w >> 8) & 0xffu);
  return f2v{sw8d(b0), sw8d(b1)};
#endif
}
// acc += 4 fp8 weights (one dword) . 4 f32 activations (as 2 pk-fma)
__device__ __forceinline__ f2v dotq(uint w, float4 a, f2v acc) {
  acc += dec2<false>(w) * f2v{a.x, a.y};
  acc += dec2<true>(w)  * f2v{a.z, a.w};
  return acc;
}

// ---------------------------------------------------------------------------
// Pack kernel:
//   Whh8q[k16][j]  k16<16, j<1024 : uint4 = fp8(16*W_hh[j][16k..+15]) (256 KB)
//   Wd8q [k16][m]  k16<32, m<256  : uint4 = fp8(16*W_d[m][16k..+15])  (128 KB)
//   Ud8  [m8][n]   m8<32, n<256   : uint4 = f16(U_d[n][8m8..+7])      (128 KB)
//   Wyt  [k][h]    k<512          : float = W_y[h][k]                 (512 KB)
// grid 208 x 256
// ---------------------------------------------------------------------------
__global__ __launch_bounds__(256)
void pack_weights(const float* __restrict__ W_d,
                  const float* __restrict__ W_hh,
                  const float* __restrict__ U_d,
                  const float* __restrict__ W_y,
                  uint4* __restrict__ Whh8q,
                  uint4* __restrict__ Wd8q,
                  uint4* __restrict__ Ud8,
                  float* __restrict__ Wyt) {
  const int blk = blockIdx.x, tid = threadIdx.x;
  if (blk < 16) {                        // Whh8q
    const int k16 = blk;
    #pragma unroll
    for (int q = 0; q < 4; ++q) {
      const int j = tid + 256 * q;
      const float* wr = W_hh + (size_t)j * 256 + 16 * k16;
      float4 a = ld4(wr), b = ld4(wr + 4), c = ld4(wr + 8), d = ld4(wr + 12);
      uint4 u;
      u.x = pk_fp8x4(16.f * a.x, 16.f * a.y, 16.f * a.z, 16.f * a.w);
      u.y = pk_fp8x4(16.f * b.x, 16.f * b.y, 16.f * b.z, 16.f * b.w);
      u.z = pk_fp8x4(16.f * c.x, 16.f * c.y, 16.f * c.z, 16.f * c.w);
      u.w = pk_fp8x4(16.f * d.x, 16.f * d.y, 16.f * d.z, 16.f * d.w);
      Whh8q[k16 * 1024 + j] = u;
    }
  } else if (blk < 48) {                 // Wd8q
    const int k16 = blk - 16;
    const float* wr = W_d + (size_t)tid * 512 + 16 * k16;
    float4 a = ld4(wr), b = ld4(wr + 4), c = ld4(wr + 8), d = ld4(wr + 12);
    uint4 u;
    u.x = pk_fp8x4(16.f * a.x, 16.f * a.y, 16.f * a.z, 16.f * a.w);
    u.y = pk_fp8x4(16.f * b.x, 16.f * b.y, 16.f * b.z, 16.f * b.w);
    u.z = pk_fp8x4(16.f * c.x, 16.f * c.y, 16.f * c.z, 16.f * c.w);
    u.w = pk_fp8x4(16.f * d.x, 16.f * d.y, 16.f * d.z, 16.f * d.w);
    Wd8q[k16 * 256 + tid] = u;
  } else if (blk < 80) {                 // Ud8 (f16, for one-time Y1 build)
    const int m8 = blk - 48;
    float4 a = ld4(U_d + (size_t)tid * 256 + 8 * m8);
    float4 b = ld4(U_d + (size_t)tid * 256 + 8 * m8 + 4);
    Ud8[m8 * 256 + tid] = uint4{pk2(a.x, a.y), pk2(a.z, a.w),
                                pk2(b.x, b.y), pk2(b.z, b.w)};
  } else {                               // Wyt transpose
    const int k0 = (blk - 80) * 4;
    float4 w = ld4(W_y + (size_t)tid * 512 + k0);
    Wyt[(k0 + 0) * 256 + tid] = w.x;
    Wyt[(k0 + 1) * 256 + tid] = w.y;
    Wyt[(k0 + 2) * 256 + tid] = w.z;
    Wyt[(k0 + 3) * 256 + tid] = w.w;
  }
}

// ---------------------------------------------------------------------------
// Main kernel: one 1024-thread wg per batch element, fully independent.
// Waves 0-7: gates. Waves 8-15: x1 -> scores -> softmax; waves 8-11 LSTM.
// ---------------------------------------------------------------------------
__global__ __launch_bounds__(NT, 4)
void fused(const float* __restrict__ enc,      // (T,B,M)
           const float* __restrict__ yv,       // (B,T,1)
           const float* __restrict__ b_Wd,     // (M)
           const float* __restrict__ v_d,      // (1,M)
           const float* __restrict__ w_tilda,  // (1,M+1)
           const float* __restrict__ b_wt,     // (1)
           const float* __restrict__ W_ih,     // (4H,1)
           const float* __restrict__ b_ih,     // (4H)
           const float* __restrict__ b_hh,     // (4H)
           const float* __restrict__ b_Wy,     // (H)
           const float* __restrict__ v_y,      // (1,H)
           const float* __restrict__ b_vy,     // (1)
           const uint4* __restrict__ Whh8q,
           const uint4* __restrict__ Wd8q,
           const uint4* __restrict__ Ud8,
           const float* __restrict__ Wyt,
           ushort* __restrict__ Y1,            // (B,T,M) f16 scratch
           float* __restrict__ out)            // (B,1)
{
  __shared__ __align__(16) float dsp_s[2 * Hx];     // [d|sp] f32
  __shared__ __align__(16) float xq_s[2 * 16 * XS]; // x1 K-half partials, swz
  __shared__ __align__(16) float vd_s[16 * XS];     // v_d swizzled
  __shared__ float gates_s[1024];                   // gates; epilogue partials
  __shared__ float dcfin_s[2 * Hx];                 // [d|c] fp32 (epilogue)
  __shared__ float l_s[Tx];
  __shared__ uint  beta2_s[Tx / 2];                 // beta packed f16 pairs
  __shared__ float e_s[Tx];                         // E_t
  __shared__ float red_s[4];
  __shared__ float ytil_s;
  __shared__ unsigned flagX, flagL;

  const int b   = blockIdx.x;
  const int tid = threadIdx.x;     // 0..1023
  const int h   = tid & 255;
  const int p   = tid >> 8;        // 0..3
  const size_t BM = (size_t)Bx * Mx;

  // ---- stage 0: params, state, flags ----
  if (tid < 256) vd_s[xsw(tid)] = v_d[tid];
  if (tid < 512) dsp_s[tid] = 0.0f;
  if (tid == 0) { flagX = 0u; flagL = 0u; }

  float bj0 = 0.f, bj1 = 0.f;                  // gate waves
  if (tid < 512) { bj0 = b_ih[tid] + b_hh[tid]; bj1 = b_ih[tid + 512] + b_hh[tid + 512]; }
  float bWd_r = 0.f;                           // x1 half-0 threads
  if (tid >= 512 && tid < 768) bWd_r = b_Wd[tid - 512];
  float wih0 = 0.f, wih1 = 0.f, wih2 = 0.f, wih3 = 0.f;  // LSTM threads
  if (tid >= 512 && tid < 768) {
    const int hh = tid - 512;
    wih0 = W_ih[hh]; wih1 = W_ih[hh + 256]; wih2 = W_ih[hh + 512]; wih3 = W_ih[hh + 768];
  }
  float yv_r = 0.f;                            // softmax wave
  if (tid >= 512 && tid < 576) yv_r = yv[b * Tx + (tid - 512)];
  const float wty = w_tilda[Mx];
  const float bwt = b_wt[0];

  // ---- stage 0b: E_t = sum_m w~_m enc[t][b][m] (global reads, one-time) ----
  if (tid < Tx) {
    const float* er = enc + (size_t)tid * BM + (size_t)b * Mx;
    float acc = 0.0f;
    for (int m = 0; m < Mx; m += 4) {
      float4 e4 = ld4(er + m);
      float4 w4 = ld4(w_tilda + m);
      acc += e4.x * w4.x + e4.y * w4.y + e4.z * w4.z + e4.w * w4.w;
    }
    e_s[tid] = acc;
  }

  // ---- stage 1: Y1[b] = enc[b] @ U_d^T (packed-fp32 FMA, f16 weights) ----
  {
    const int n = h;
    const float* eb = enc + (size_t)b * Mx;
    for (int tb = p * 16; tb < p * 16 + 16; tb += 8) {
      f2v acc2[8];
      #pragma unroll
      for (int j = 0; j < 8; ++j) acc2[j] = f2v{0.f, 0.f};
      #pragma unroll 2
      for (int m8 = 0; m8 < 32; ++m8) {
        uint4 u = Ud8[m8 * 256 + n];
        f2v w01 = f2v{h2f((ushort)u.x), h2f((ushort)(u.x >> 16))};
        f2v w23 = f2v{h2f((ushort)u.y), h2f((ushort)(u.y >> 16))};
        f2v w45 = f2v{h2f((ushort)u.z), h2f((ushort)(u.z >> 16))};
        f2v w67 = f2v{h2f((ushort)u.w), h2f((ushort)(u.w >> 16))};
        #pragma unroll
        for (int j = 0; j < 8; ++j) {
          const float* ep = eb + (size_t)(tb + j) * BM + 8 * m8;
          float4 ea = ld4(ep), eb4 = ld4(ep + 4);
          acc2[j] += f2v{ea.x, ea.y} * w01;
          acc2[j] += f2v{ea.z, ea.w} * w23;
          acc2[j] += f2v{eb4.x, eb4.y} * w45;
          acc2[j] += f2v{eb4.z, eb4.w} * w67;
        }
      }
      #pragma unroll
      for (int j = 0; j < 8; ++j)
        Y1[((size_t)b * Tx + tb + j) * Mx + n] = f2h(acc2[j].x + acc2[j].y);
    }
  }
  __syncthreads();  // S1: dsp_s, vd_s, e_s, flags, Y1 ready

  float sp_reg = 0.0f;   // LSTM threads (tid 512..767)

  for (int t = 0; t < Tx; ++t) {
    if (tid < 512) {
      // ===== GATE WAVES: outputs j=tid, tid+512; fp8 stream 256 KB =====
      f2v ga = f2v{0.f, 0.f}, gb = f2v{0.f, 0.f};
      const uint4* wp = Whh8q + tid;
      #pragma unroll 2
      for (int c = 0; c < 16; ++c) {
        uint4 wa = wp[c * 1024];
        uint4 wb = wp[c * 1024 + 512];
        const float4* ap = (const float4*)dsp_s + 4 * c;   // d[16c..16c+15]
        float4 a0 = ap[0], a1 = ap[1], a2 = ap[2], a3 = ap[3];
        ga = dotq(wa.x, a0, ga); ga = dotq(wa.y, a1, ga);
        ga = dotq(wa.z, a2, ga); ga = dotq(wa.w, a3, ga);
        gb = dotq(wb.x, a0, gb); gb = dotq(wb.y, a1, gb);
        gb = dotq(wb.z, a2, gb); gb = dotq(wb.w, a3, gb);
      }
      gates_s[tid]       = (ga.x + ga.y) * 0.0625f + bj0;
      gates_s[tid + 512] = (gb.x + gb.y) * 0.0625f + bj1;
    } else {
      // ===== SCORE WAVES =====
      const int idx = tid - 512;               // 0..511
      const int m = idx & 255, q = idx >> 8;   // x1: output m, K-half q
      {
        f2v xa2 = f2v{0.f, 0.f};
        const uint4* xp = Wd8q + m + (q * 16) * 256;
        #pragma unroll 2
        for (int i = 0; i < 16; ++i) {
          uint4 u = xp[i * 256];
          const float4* ap = (const float4*)dsp_s + 64 * q + 4 * i;
          float4 a0 = ap[0], a1 = ap[1], a2 = ap[2], a3 = ap[3];
          xa2 = dotq(u.x, a0, xa2); xa2 = dotq(u.y, a1, xa2);
          xa2 = dotq(u.z, a2, xa2); xa2 = dotq(u.w, a3, xa2);
        }
        xq_s[q * (16 * XS) + xsw(m)] = (xa2.x + xa2.y) * 0.0625f
                                     + (q == 0 ? bWd_r : 0.0f);
      }
      __threadfence_block();
      if ((threadIdx.x & 63) == 0)
        __hip_atomic_fetch_add(&flagX, 1u, __ATOMIC_RELEASE, __HIP_MEMORY_SCOPE_WORKGROUP);
      const unsigned tgtX = 8u * (unsigned)(t + 1);
      while (__hip_atomic_load(&flagX, __ATOMIC_ACQUIRE, __HIP_MEMORY_SCOPE_WORKGROUP) < tgtX) {}

      // scores: 8 lanes/query, lane covers 32 m's
      {
        const int tq = idx >> 3, lq = idx & 7;
        const ushort* y1r = Y1 + ((size_t)b * Tx + tq) * Mx + lq * 32;
        float ps = 0.0f;
        #pragma unroll
        for (int g = 0; g < 8; ++g) {
          const int c   = 2 * lq + (g >> 2);
          const int off = c * XS + 4 * (g & 3);
          float4 xa0 = *(const float4*)(xq_s + off);
          float4 xa1 = *(const float4*)(xq_s + 16 * XS + off);
          float4 vv  = *(const float4*)(vd_s + off);
          uint2 yy = *(const uint2*)(y1r + 4 * g);
          ps += tanh_fast(xa0.x + xa1.x + h2f((ushort)yy.x)) * vv.x
              + tanh_fast(xa0.y + xa1.y + h2f((ushort)(yy.x >> 16))) * vv.y
              + tanh_fast(xa0.z + xa1.z + h2f((ushort)yy.y)) * vv.z
              + tanh_fast(xa0.w + xa1.w + h2f((ushort)(yy.y >> 16))) * vv.w;
        }
        ps += __shfl_xor(ps, 1, 64);
        ps += __shfl_xor(ps, 2, 64);
        ps += __shfl_xor(ps, 4, 64);
        if (lq == 0) l_s[tq] = ps;
      }
      __threadfence_block();
      if ((threadIdx.x & 63) == 0)
        __hip_atomic_fetch_add(&flagL, 1u, __ATOMIC_RELEASE, __HIP_MEMORY_SCOPE_WORKGROUP);

      if (idx < 64) {
        // softmax + beta pack + ytil (wave 8 only)
        const unsigned tgtL = 8u * (unsigned)(t + 1);
        while (__hip_atomic_load(&flagL, __ATOMIC_ACQUIRE, __HIP_MEMORY_SCOPE_WORKGROUP) < tgtL) {}
        float v = l_s[idx];
        float mx = v;
        #pragma unroll
        for (int o = 1; o < 64; o <<= 1) mx = fmaxf(mx, __shfl_xor(mx, o, 64));
        float e = __expf(v - mx);
        float sm = e;
        #pragma unroll
        for (int o = 1; o < 64; o <<= 1) sm += __shfl_xor(sm, o, 64);
        float beta = e / sm;
        float bnext = __shfl_xor(beta, 1, 64);
        if ((idx & 1) == 0) beta2_s[idx >> 1] = pk2(beta, bnext);
        float term = beta * e_s[idx] + ((idx == t) ? (wty * yv_r + bwt) : 0.0f);
        float yt = wave_sum(term);
        if (idx == 0) ytil_s = yt;
      }
    }
    __syncthreads();  // B_end: gates_s + ytil_s (+beta2_s) ready

    // ===== LSTM cell: threads 512..767 =====
    if (tid >= 512 && tid < 768) {
      const int hh = tid - 512;
      const float ytil = ytil_s;
      float fi = sigm(gates_s[hh]       + ytil * wih0);
      float ff = sigm(gates_s[256 + hh] + ytil * wih1);
      float fg = tanh_fast(gates_s[512 + hh] + ytil * wih2);
      float fo = sigm(gates_s[768 + hh] + ytil * wih3);
      float spn = ff * sp_reg + fi * fg;
      float dn  = fo * tanh_fast(spn);
      sp_reg = spn;
      dsp_s[hh]       = dn;
      dsp_s[256 + hh] = spn;
      if (t == Tx - 1) dcfin_s[hh] = dn;
    }
    __syncthreads();  // B_state: d/sp(t) ready
  }

  // ===== one-time context c (beta of t=63): threads >=512, 2 lanes per m ====
  if (tid >= 512) {
    const int idx = tid - 512;
    const int m = idx >> 1, q = idx & 1;
    float acc = 0.0f;
    #pragma unroll 4
    for (int j = 0; j < 32; ++j) {
      const int tt = q * 32 + j;
      uint bp = beta2_s[tt >> 1];
      float bb = (tt & 1) ? h2f((ushort)(bp >> 16)) : h2f((ushort)bp);
      acc += bb * enc[(size_t)tt * BM + (size_t)b * Mx + m];
    }
    acc += __shfl_xor(acc, 1, 64);
    if (q == 0) dcfin_s[256 + m] = acc;
  }
  __syncthreads();

  // ===== Epilogue: out[b] = v_y . (W_y @ [d|c] + b_Wy) + b_vy =====
  {
    float a = 0.0f;
    const float* wy = Wyt + h;
    for (int k = 128 * p; k < 128 * p + 128; ++k)
      a += wy[(size_t)k * 256] * dcfin_s[k];
    gates_s[p * 256 + h] = a;     // gates_s reused as epilogue partials
  }
  __syncthreads();
  if (tid < 256) {
    float aa = gates_s[h] + gates_s[256 + h] + gates_s[512 + h] + gates_s[768 + h]
             + b_Wy[h];
    float po = aa * v_y[h];
    po = wave_sum(po);
    if ((tid & 63) == 0) red_s[tid >> 6] = po;
  }
  __syncthreads();
  if (tid == 0) out[b] = red_s[0] + red_s[1] + red_s[2] + red_s[3] + b_vy[0];
}

extern "C" void kernel_launch(void* const* d_in, const int* in_sizes, int n_in,
                              void* d_out, int out_size, void* d_ws, size_t ws_size,
                              hipStream_t stream) {
  const float* enc     = (const float*)d_in[0];
  const float* yv      = (const float*)d_in[1];
  const float* W_d     = (const float*)d_in[2];
  const float* b_Wd    = (const float*)d_in[3];
  const float* U_d     = (const float*)d_in[4];
  const float* v_d     = (const float*)d_in[5];
  const float* w_tilda = (const float*)d_in[6];
  const float* b_wt    = (const float*)d_in[7];
  const float* W_ih    = (const float*)d_in[8];
  const float* W_hh    = (const float*)d_in[9];
  const float* b_ih    = (const float*)d_in[10];
  const float* b_hh    = (const float*)d_in[11];
  const float* W_y     = (const float*)d_in[12];
  const float* b_Wy    = (const float*)d_in[13];
  const float* v_y     = (const float*)d_in[14];
  const float* b_vy    = (const float*)d_in[15];
  float* outp = (float*)d_out;

  char* ws = (char*)d_ws;
  uint4* Whh8q = (uint4*)ws;                               // 256 KB
  uint4* Wd8q  = (uint4*)(ws + (256 << 10));               // 128 KB
  uint4* Ud8   = (uint4*)(ws + (384 << 10));               // 128 KB
  float* Wyt   = (float*)(ws + (512 << 10));               // 512 KB
  ushort* Y1   = (ushort*)(ws + (1024 << 10));             // 8 MB

  hipLaunchKernelGGL(pack_weights, dim3(208), dim3(256), 0, stream,
                     W_d, W_hh, U_d, W_y, Whh8q, Wd8q, Ud8, Wyt);
  hipLaunchKernelGGL(fused, dim3(Bx), dim3(NT), 0, stream,
                     enc, yv, b_Wd, v_d, w_tilda, b_wt, W_ih, b_ih, b_hh,
                     b_Wy, v_y, b_vy, Whh8q, Wd8q, Ud8, Wyt, Y1, outp);
}